// Round 1
// baseline (420.399 us; speedup 1.0000x reference)
//
#include <hip/hip_runtime.h>
#include <stdint.h>

#define N_TOK 8192
#define D_DIM 1024
#define E_NUM 8

typedef float f32x4 __attribute__((ext_vector_type(4)));
typedef __bf16 bf16x8 __attribute__((ext_vector_type(8)));

__device__ __forceinline__ unsigned short f32_to_bf16_bits(float f) {
  union { float f; uint32_t u; } v; v.f = f;
  uint32_t u = v.u;
  uint32_t r = u + 0x7fffu + ((u >> 16) & 1u);  // RNE
  return (unsigned short)(r >> 16);
}

// ---------------- routing: fp64 logits -> softmax + argmax ----------------
// One wave per token. fp64 so argmax matches the exact/np reference (bf16 or
// sloppy fp32 logits would flip ~60/8192 tokens -> absmax O(1) fail).
__global__ __launch_bounds__(256) void routing_kernel(
    const float* __restrict__ x, const float* __restrict__ Wp,
    const float* __restrict__ bp, float* __restrict__ probs_out,
    float* __restrict__ chosenF, int* __restrict__ chosen,
    int* __restrict__ counts) {
  const int wave = threadIdx.x >> 6;
  const int lane = threadIdx.x & 63;
  const int token = blockIdx.x * 4 + wave;
  if (token >= N_TOK) return;
  const float* xr = x + (size_t)token * D_DIM;
  double acc[E_NUM];
#pragma unroll
  for (int e = 0; e < E_NUM; e++) acc[e] = 0.0;
  for (int d = lane; d < D_DIM; d += 64) {
    double xv = (double)xr[d];
    const float4* w4 = reinterpret_cast<const float4*>(Wp + (size_t)d * E_NUM);
    float4 w0 = w4[0], w1 = w4[1];
    acc[0] += xv * (double)w0.x;
    acc[1] += xv * (double)w0.y;
    acc[2] += xv * (double)w0.z;
    acc[3] += xv * (double)w0.w;
    acc[4] += xv * (double)w1.x;
    acc[5] += xv * (double)w1.y;
    acc[6] += xv * (double)w1.z;
    acc[7] += xv * (double)w1.w;
  }
#pragma unroll
  for (int e = 0; e < E_NUM; e++) {
#pragma unroll
    for (int off = 32; off > 0; off >>= 1) acc[e] += __shfl_xor(acc[e], off);
  }
  if (lane == 0) {
    double lg[E_NUM];
#pragma unroll
    for (int e = 0; e < E_NUM; e++) lg[e] = acc[e] + (double)bp[e];
    int best = 0;
    double bv = lg[0];
#pragma unroll
    for (int e = 1; e < E_NUM; e++)
      if (lg[e] > bv) { bv = lg[e]; best = e; }  // strict > == first-max (jnp.argmax)
    double s = 0.0, ex[E_NUM];
#pragma unroll
    for (int e = 0; e < E_NUM; e++) { ex[e] = exp(lg[e] - bv); s += ex[e]; }
    double inv = 1.0 / s;
#pragma unroll
    for (int e = 0; e < E_NUM; e++)
      probs_out[(size_t)token * E_NUM + e] = (float)(ex[e] * inv);
    chosenF[token] = (float)best;
    chosen[token] = best;
    atomicAdd(&counts[best], 1);
  }
}

// ---------------- prefix over 8 experts (tiny) ----------------
__global__ void scan_kernel(const int* __restrict__ counts,
                            int* __restrict__ offsets, int* __restrict__ cursors) {
  if (threadIdx.x == 0 && blockIdx.x == 0) {
    int off = 0;
    for (int e = 0; e < E_NUM; e++) { offsets[e] = off; cursors[e] = off; off += counts[e]; }
    offsets[E_NUM] = off;
  }
}

// ---------------- scatter token ids into per-expert groups ----------------
__global__ __launch_bounds__(256) void scatter_kernel(const int* __restrict__ chosen,
                                                      int* __restrict__ cursors,
                                                      int* __restrict__ perm) {
  int n = blockIdx.x * blockDim.x + threadIdx.x;
  if (n < N_TOK) {
    int e = chosen[n];
    int p = atomicAdd(&cursors[e], 1);  // in-group order irrelevant (per-token outputs)
    perm[p] = n;
  }
}

// ---------------- x fp32 -> bf16 (vectorized) ----------------
__global__ __launch_bounds__(256) void cast_kernel(const float* __restrict__ src,
                                                   unsigned short* __restrict__ dst,
                                                   int n8) {
  int i = blockIdx.x * blockDim.x + threadIdx.x;
  if (i >= n8) return;
  const float4* s = reinterpret_cast<const float4*>(src) + (size_t)i * 2;
  float4 a = s[0], b = s[1];
  union { unsigned short us[8]; uint4 v; } o;
  o.us[0] = f32_to_bf16_bits(a.x);
  o.us[1] = f32_to_bf16_bits(a.y);
  o.us[2] = f32_to_bf16_bits(a.z);
  o.us[3] = f32_to_bf16_bits(a.w);
  o.us[4] = f32_to_bf16_bits(b.x);
  o.us[5] = f32_to_bf16_bits(b.y);
  o.us[6] = f32_to_bf16_bits(b.z);
  o.us[7] = f32_to_bf16_bits(b.w);
  reinterpret_cast<uint4*>(dst)[i] = o.v;
}

// ---------------- per-expert 1024x1024 fp32 -> bf16 transpose ----------------
// dst[e][c][r] = src[e][r][c]; both MFMA operands need k-contiguous storage,
// so weights [K][N] must become [N][K].
__global__ __launch_bounds__(256) void transpose_cast_kernel(
    const float* __restrict__ src, unsigned short* __restrict__ dst) {
  __shared__ __align__(16) unsigned short T[64][72];  // +8 pad: decent banks, keeps 8B align
  const int e = blockIdx.z;
  const int r0 = blockIdx.y * 64, c0 = blockIdx.x * 64;
  const float* S = src + ((size_t)e << 20);
  unsigned short* O = dst + ((size_t)e << 20);
  const int t = threadIdx.x;
  const int rr = t >> 4;
  const int cc = (t & 15) * 4;
#pragma unroll
  for (int p = 0; p < 4; p++) {
    int r = p * 16 + rr;
    float4 v = *reinterpret_cast<const float4*>(S + (size_t)(r0 + r) * 1024 + c0 + cc);
    T[cc + 0][r] = f32_to_bf16_bits(v.x);
    T[cc + 1][r] = f32_to_bf16_bits(v.y);
    T[cc + 2][r] = f32_to_bf16_bits(v.z);
    T[cc + 3][r] = f32_to_bf16_bits(v.w);
  }
  __syncthreads();
#pragma unroll
  for (int p = 0; p < 4; p++) {
    int c = p * 16 + rr;
    ushort4 o = *reinterpret_cast<const ushort4*>(&T[c][cc]);
    *reinterpret_cast<ushort4*>(O + (size_t)(c0 + c) * 1024 + r0 + cc) = o;
  }
}

// ---------------- grouped GEMM: 128x128 tile, BK=64, 4 waves ----------------
// MODE 0: h = relu(x[perm] @ W1t^T + b1) -> hb (bf16, compacted by group pos)
// MODE 1: out[perm] = hb @ W2t^T + b2    (fp32 scatter)
// A fragment: lane holds A[wrow + lr][kk + lk*8 .. +7]  (contiguous 16B ds_read)
// B fragment: lane holds B[k][col] from [N][K]-stored Wt, same contiguous read
// C/D: col = lane&15, row = (lane>>4)*4 + reg   [verified mapping, learn_hip m89]
template <int MODE>
__global__ __launch_bounds__(256) void moe_gemm_kernel(
    const unsigned short* __restrict__ Abase,  // xb (MODE0) / hb (MODE1)
    const unsigned short* __restrict__ Wt,     // bf16 [E][1024(n)][1024(k)]
    const float* __restrict__ bias,            // [E][1024]
    const int* __restrict__ offsets, const int* __restrict__ perm,
    unsigned short* __restrict__ hb, float* __restrict__ out) {
  constexpr int LDA = 72;  // ushorts per LDS row (64 data + 8 pad -> 144B stride)
  __shared__ __align__(16) unsigned short As[2][128 * LDA];
  __shared__ __align__(16) unsigned short Bs[2][128 * LDA];

  const int e = blockIdx.x >> 6;
  const int tm = blockIdx.x & 63;
  const int g0 = offsets[e];
  const int m_count = offsets[e + 1] - g0;
  const int m0 = tm * 128;
  if (m0 >= m_count) return;  // uniform early-exit (before any barrier)
  const int n0 = blockIdx.y * 128;

  const int tid = threadIdx.x;
  const int srow = tid >> 3;   // 0..31
  const int sslot = tid & 7;   // 16B slot within 128B k-row

  const unsigned short* aptr[4];
  const unsigned short* bptr[4];
  const unsigned short* WtE = Wt + ((size_t)e << 20);
#pragma unroll
  for (int t = 0; t < 4; t++) {
    int r = srow + 32 * t;
    int gr = g0 + m0 + r;
    int grc = gr < (N_TOK - 1) ? gr : (N_TOK - 1);  // clamp partial tiles
    int row_index = (MODE == 0) ? perm[grc] : grc;
    aptr[t] = Abase + (size_t)row_index * 1024 + sslot * 8;
    bptr[t] = WtE + (size_t)(n0 + r) * 1024 + sslot * 8;
  }
  const int woff = srow * LDA + sslot * 8;

  f32x4 acc[4][4];
  const f32x4 zero4 = {0.f, 0.f, 0.f, 0.f};
#pragma unroll
  for (int i = 0; i < 4; i++)
#pragma unroll
    for (int j = 0; j < 4; j++) acc[i][j] = zero4;

  const int wid = tid >> 6, lane = tid & 63;
  const int wr = wid >> 1, wc = wid & 1;
  const int lr = lane & 15, lk = lane >> 4;

  auto compute = [&](const unsigned short* cA, const unsigned short* cB) {
#pragma unroll
    for (int kk = 0; kk < 64; kk += 32) {
      bf16x8 af[4], bfr[4];
#pragma unroll
      for (int mf = 0; mf < 4; mf++)
        af[mf] = *reinterpret_cast<const bf16x8*>(
            &cA[(wr * 64 + mf * 16 + lr) * LDA + kk + lk * 8]);
#pragma unroll
      for (int nf = 0; nf < 4; nf++)
        bfr[nf] = *reinterpret_cast<const bf16x8*>(
            &cB[(wc * 64 + nf * 16 + lr) * LDA + kk + lk * 8]);
#pragma unroll
      for (int mf = 0; mf < 4; mf++)
#pragma unroll
        for (int nf = 0; nf < 4; nf++)
          acc[mf][nf] = __builtin_amdgcn_mfma_f32_16x16x32_bf16(
              af[mf], bfr[nf], acc[mf][nf], 0, 0, 0);
    }
  };

  // prologue: stage K-tile 0
  uint4 av[4], bv[4];
#pragma unroll
  for (int t = 0; t < 4; t++) {
    av[t] = *reinterpret_cast<const uint4*>(aptr[t]);
    bv[t] = *reinterpret_cast<const uint4*>(bptr[t]);
  }
#pragma unroll
  for (int t = 0; t < 4; t++) {
    *reinterpret_cast<uint4*>(&As[0][woff + 32 * t * LDA]) = av[t];
    *reinterpret_cast<uint4*>(&Bs[0][woff + 32 * t * LDA]) = bv[t];
  }
  __syncthreads();

  int cur = 0;
  for (int kt = 0; kt < 15; kt++) {
    const int k_next = (kt + 1) * 64;
    // issue-early: next tile's global loads hide under compute (T14)
#pragma unroll
    for (int t = 0; t < 4; t++) {
      av[t] = *reinterpret_cast<const uint4*>(aptr[t] + k_next);
      bv[t] = *reinterpret_cast<const uint4*>(bptr[t] + k_next);
    }
    compute(As[cur], Bs[cur]);
    // write-late into the other buffer (last read at iter kt-1, barrier since)
#pragma unroll
    for (int t = 0; t < 4; t++) {
      *reinterpret_cast<uint4*>(&As[cur ^ 1][woff + 32 * t * LDA]) = av[t];
      *reinterpret_cast<uint4*>(&Bs[cur ^ 1][woff + 32 * t * LDA]) = bv[t];
    }
    __syncthreads();
    cur ^= 1;
  }
  compute(As[cur], Bs[cur]);

  // epilogue
  const int mlim = m_count - m0;
#pragma unroll
  for (int nf = 0; nf < 4; nf++) {
    const int c = n0 + wc * 64 + nf * 16 + lr;
    const float bval = bias[(e << 10) + c];
#pragma unroll
    for (int mf = 0; mf < 4; mf++) {
#pragma unroll
      for (int j = 0; j < 4; j++) {
        const int lrow = wr * 64 + mf * 16 + lk * 4 + j;
        if (lrow < mlim) {
          float v = acc[mf][nf][j] + bval;
          if (MODE == 0) {
            v = v > 0.f ? v : 0.f;
            hb[(size_t)(g0 + m0 + lrow) * 1024 + c] = f32_to_bf16_bits(v);
          } else {
            int token = perm[g0 + m0 + lrow];
            out[(size_t)token * 1024 + c] = v;
          }
        }
      }
    }
  }
}

// ---------------- launch ----------------
extern "C" void kernel_launch(void* const* d_in, const int* in_sizes, int n_in,
                              void* d_out, int out_size, void* d_ws, size_t ws_size,
                              hipStream_t stream) {
  const float* x = (const float*)d_in[0];
  const float* Wp = (const float*)d_in[1];
  const float* bp = (const float*)d_in[2];
  const float* W1 = (const float*)d_in[3];
  const float* b1 = (const float*)d_in[4];
  const float* W2 = (const float*)d_in[5];
  const float* b2 = (const float*)d_in[6];

  float* out = (float*)d_out;                            // [8192][1024]
  float* probs = out + (size_t)N_TOK * D_DIM;            // [8192][8]
  float* chosenF = probs + (size_t)N_TOK * E_NUM;        // [8192]

  char* ws = (char*)d_ws;
  int* chosen = (int*)(ws + 0);              // 32768 B
  int* counts = (int*)(ws + 32768);          // 32 B
  int* cursors = (int*)(ws + 32800);         // 32 B
  int* offsets = (int*)(ws + 32832);         // 64 B
  int* perm = (int*)(ws + 33024);            // 32768 B
  unsigned short* xb = (unsigned short*)(ws + 66048);                 // 16 MB
  unsigned short* Wt = (unsigned short*)(ws + 66048 + 16777216);      // 16 MB (W1t then W2t)
  unsigned short* hb = (unsigned short*)(ws + 66048 + 2 * 16777216);  // 16 MB
  // total ws use: 48.1 MB

  hipMemsetAsync(counts, 0, 32, stream);
  routing_kernel<<<N_TOK / 4, 256, 0, stream>>>(x, Wp, bp, probs, chosenF, chosen, counts);
  scan_kernel<<<1, 1, 0, stream>>>(counts, offsets, cursors);
  scatter_kernel<<<N_TOK / 256, 256, 0, stream>>>(chosen, cursors, perm);
  cast_kernel<<<(N_TOK * D_DIM / 8) / 256, 256, 0, stream>>>(x, xb, N_TOK * D_DIM / 8);
  transpose_cast_kernel<<<dim3(16, 16, 8), 256, 0, stream>>>(W1, Wt);
  moe_gemm_kernel<0><<<dim3(E_NUM * 64, 8), 256, 0, stream>>>(xb, Wt, b1, offsets, perm, hb, nullptr);
  transpose_cast_kernel<<<dim3(16, 16, 8), 256, 0, stream>>>(W2, Wt);  // reuse Wt (W1t dead)
  moe_gemm_kernel<1><<<dim3(E_NUM * 64, 8), 256, 0, stream>>>(hb, Wt, b2, offsets, perm, nullptr, out);
}

// Round 2
// 263.868 us; speedup vs baseline: 1.5932x; 1.5932x over previous
//
#include <hip/hip_runtime.h>
#include <stdint.h>

#define N_TOK 8192
#define D_DIM 1024
#define E_NUM 8

typedef float f32x4 __attribute__((ext_vector_type(4)));
typedef __bf16 bf16x8 __attribute__((ext_vector_type(8)));

__device__ __forceinline__ unsigned short f32_to_bf16_bits(float f) {
  union { float f; uint32_t u; } v; v.f = f;
  uint32_t u = v.u;
  uint32_t r = u + 0x7fffu + ((u >> 16) & 1u);  // RNE
  return (unsigned short)(r >> 16);
}

__device__ __forceinline__ void load_lds16(const void* g, void* l) {
  // async global->LDS, 16B/lane, dest = uniform base + lane*16
  __builtin_amdgcn_global_load_lds(
      (const __attribute__((address_space(1))) void*)g,
      (__attribute__((address_space(3))) void*)l, 16, 0, 0);
}

// ---------- routing (fp64 logits -> softmax/argmax) + x->bf16 cast, fused ----------
// fp64 so argmax matches the np reference exactly (bf16/f32 logits flip tokens).
__global__ __launch_bounds__(256) void routing_kernel(
    const float* __restrict__ x, const float* __restrict__ Wp,
    const float* __restrict__ bp, float* __restrict__ probs_out,
    float* __restrict__ chosenF, int* __restrict__ chosen,
    int* __restrict__ counts, unsigned short* __restrict__ xb) {
  const int wave = threadIdx.x >> 6;
  const int lane = threadIdx.x & 63;
  const int token = blockIdx.x * 4 + wave;
  if (token >= N_TOK) return;
  const float* xr = x + (size_t)token * D_DIM;
  unsigned short* xbr = xb + (size_t)token * D_DIM;
  double acc[E_NUM];
#pragma unroll
  for (int e = 0; e < E_NUM; e++) acc[e] = 0.0;
#pragma unroll
  for (int it = 0; it < 4; it++) {
    const int d0 = it * 256 + lane * 4;
    float4 xv = *reinterpret_cast<const float4*>(xr + d0);
    ushort4 o;
    o.x = f32_to_bf16_bits(xv.x);
    o.y = f32_to_bf16_bits(xv.y);
    o.z = f32_to_bf16_bits(xv.z);
    o.w = f32_to_bf16_bits(xv.w);
    *reinterpret_cast<ushort4*>(xbr + d0) = o;
    float xs[4] = {xv.x, xv.y, xv.z, xv.w};
#pragma unroll
    for (int c = 0; c < 4; c++) {
      const float4* w4 = reinterpret_cast<const float4*>(Wp + (size_t)(d0 + c) * E_NUM);
      float4 w0 = w4[0], w1 = w4[1];
      double xd = (double)xs[c];
      acc[0] += xd * (double)w0.x;
      acc[1] += xd * (double)w0.y;
      acc[2] += xd * (double)w0.z;
      acc[3] += xd * (double)w0.w;
      acc[4] += xd * (double)w1.x;
      acc[5] += xd * (double)w1.y;
      acc[6] += xd * (double)w1.z;
      acc[7] += xd * (double)w1.w;
    }
  }
#pragma unroll
  for (int e = 0; e < E_NUM; e++) {
#pragma unroll
    for (int off = 32; off > 0; off >>= 1) acc[e] += __shfl_xor(acc[e], off);
  }
  if (lane == 0) {
    double lg[E_NUM];
#pragma unroll
    for (int e = 0; e < E_NUM; e++) lg[e] = acc[e] + (double)bp[e];
    int best = 0;
    double bv = lg[0];
#pragma unroll
    for (int e = 1; e < E_NUM; e++)
      if (lg[e] > bv) { bv = lg[e]; best = e; }  // strict > == first-max (jnp.argmax)
    double s = 0.0, ex[E_NUM];
#pragma unroll
    for (int e = 0; e < E_NUM; e++) { ex[e] = exp(lg[e] - bv); s += ex[e]; }
    double inv = 1.0 / s;
#pragma unroll
    for (int e = 0; e < E_NUM; e++)
      probs_out[(size_t)token * E_NUM + e] = (float)(ex[e] * inv);
    chosenF[token] = (float)best;
    chosen[token] = best;
    atomicAdd(&counts[best], 1);
  }
}

// ---------- scan (8 experts) + scatter into per-expert groups, one block ----------
__global__ __launch_bounds__(1024) void scan_scatter_kernel(
    const int* __restrict__ counts, const int* __restrict__ chosen,
    int* __restrict__ offsets, int* __restrict__ perm) {
  __shared__ int curs[E_NUM];
  const int t = threadIdx.x;
  if (t == 0) {
    int off = 0;
    for (int e = 0; e < E_NUM; e++) { offsets[e] = off; curs[e] = off; off += counts[e]; }
    offsets[E_NUM] = off;
  }
  __syncthreads();
  for (int n = t; n < N_TOK; n += 1024) {
    int e = chosen[n];
    int p = atomicAdd(&curs[e], 1);  // in-group order irrelevant
    perm[p] = n;
  }
}

// ---------- per-expert 1024x1024 fp32 -> bf16 transpose ----------
__global__ __launch_bounds__(256) void transpose_cast_kernel(
    const float* __restrict__ src, unsigned short* __restrict__ dst) {
  __shared__ __align__(16) unsigned short T[64][72];
  const int e = blockIdx.z;
  const int r0 = blockIdx.y * 64, c0 = blockIdx.x * 64;
  const float* S = src + ((size_t)e << 20);
  unsigned short* O = dst + ((size_t)e << 20);
  const int t = threadIdx.x;
  const int rr = t >> 4;
  const int cc = (t & 15) * 4;
#pragma unroll
  for (int p = 0; p < 4; p++) {
    int r = p * 16 + rr;
    float4 v = *reinterpret_cast<const float4*>(S + (size_t)(r0 + r) * 1024 + c0 + cc);
    T[cc + 0][r] = f32_to_bf16_bits(v.x);
    T[cc + 1][r] = f32_to_bf16_bits(v.y);
    T[cc + 2][r] = f32_to_bf16_bits(v.z);
    T[cc + 3][r] = f32_to_bf16_bits(v.w);
  }
  __syncthreads();
#pragma unroll
  for (int p = 0; p < 4; p++) {
    int c = p * 16 + rr;
    ushort4 o = *reinterpret_cast<const ushort4*>(&T[c][cc]);
    *reinterpret_cast<ushort4*>(O + (size_t)(c0 + c) * 1024 + r0 + cc) = o;
  }
}

// ---------- grouped GEMM: 128x128 tile, BK=64, 4 waves, m97-structure ----------
// global_load_lds (16B) -> linear LDS, single-buffered, 2 barriers per K-step.
// grid: 1-D 4096; e = bid&7 (-> bid mod 8 == XCD: expert-per-XCD L2 locality),
// slot = bid>>3, m-tile = slot>>3, n-tile = slot&7. Active blocks are the
// contiguous front of the grid -> even CU spread (fixes stride-64 aliasing).
// MODE 0: h = relu(x[perm] @ W1t^T + b1) -> hb (bf16, group-compacted)
// MODE 1: out[perm] = hb @ W2t^T + b2    (fp32 scatter)
template <int MODE>
__global__ __launch_bounds__(256) void moe_gemm_kernel(
    const unsigned short* __restrict__ Abase,  // xb (MODE0) / hb (MODE1)
    const unsigned short* __restrict__ Wt,     // bf16 [E][1024(n)][1024(k)]
    const float* __restrict__ bias,            // [E][1024]
    const int* __restrict__ offsets, const int* __restrict__ perm,
    unsigned short* __restrict__ hb, float* __restrict__ out) {
  __shared__ __align__(16) unsigned short As[128 * 64];
  __shared__ __align__(16) unsigned short Bs[128 * 64];

  const int e = blockIdx.x & 7;
  const int slot = blockIdx.x >> 3;
  const int g0 = offsets[e];
  const int m_count = offsets[e + 1] - g0;
  const int m0 = (slot >> 3) * 128;
  if (m0 >= m_count) return;  // uniform early-exit, before any barrier
  const int n0 = (slot & 7) * 128;

  const int tid = threadIdx.x;
  const int wid = tid >> 6, lane = tid & 63;
  const int lrow = lane >> 3;   // 0..7: row within the wave's 8-row stripe
  const int lchunk = lane & 7;  // 16B chunk within the 128B k-row

  const unsigned short* ga[4];
  const unsigned short* gb[4];
  unsigned short* la[4];
  unsigned short* lb[4];
  const unsigned short* WtE = Wt + ((size_t)e << 20);
#pragma unroll
  for (int t = 0; t < 4; t++) {
    const int rbase = t * 32 + wid * 8;     // wave-uniform
    const int r = rbase + lrow;             // 0..127
    int gr = g0 + m0 + r;
    if (gr > N_TOK - 1) gr = N_TOK - 1;     // clamp partial m-tiles
    const int arow = (MODE == 0) ? perm[gr] : gr;
    ga[t] = Abase + (size_t)arow * 1024 + lchunk * 8;
    gb[t] = WtE + (size_t)(n0 + r) * 1024 + lchunk * 8;
    la[t] = &As[rbase * 64];                // uniform per wave (required)
    lb[t] = &Bs[rbase * 64];
  }

  f32x4 acc[4][4];
  const f32x4 zero4 = {0.f, 0.f, 0.f, 0.f};
#pragma unroll
  for (int i = 0; i < 4; i++)
#pragma unroll
    for (int j = 0; j < 4; j++) acc[i][j] = zero4;

  const int wr = wid >> 1, wc = wid & 1;
  const int lr = lane & 15, lk = lane >> 4;

  auto stage = [&]() {
#pragma unroll
    for (int t = 0; t < 4; t++) {
      load_lds16(ga[t], la[t]);
      load_lds16(gb[t], lb[t]);
      ga[t] += 64;
      gb[t] += 64;
    }
  };
  auto compute = [&]() {
#pragma unroll
    for (int kk = 0; kk < 64; kk += 32) {
      bf16x8 af[4], bfr[4];
#pragma unroll
      for (int mf = 0; mf < 4; mf++)
        af[mf] = *reinterpret_cast<const bf16x8*>(
            &As[(wr * 64 + mf * 16 + lr) * 64 + kk + lk * 8]);
#pragma unroll
      for (int nf = 0; nf < 4; nf++)
        bfr[nf] = *reinterpret_cast<const bf16x8*>(
            &Bs[(wc * 64 + nf * 16 + lr) * 64 + kk + lk * 8]);
#pragma unroll
      for (int mf = 0; mf < 4; mf++)
#pragma unroll
        for (int nf = 0; nf < 4; nf++)
          acc[mf][nf] = __builtin_amdgcn_mfma_f32_16x16x32_bf16(
              af[mf], bfr[nf], acc[mf][nf], 0, 0, 0);
    }
  };

  stage();
  __syncthreads();  // vmcnt(0) drain + barrier: tile 0 ready
  for (int kt = 0; kt < 16; kt++) {
    compute();
    if (kt < 15) {
      __syncthreads();  // all waves done reading
      stage();
      __syncthreads();  // next tile ready
    }
  }

  // epilogue: C/D layout col=lane&15, row=(lane>>4)*4+reg [m89]
  const int mlim = m_count - m0;
#pragma unroll
  for (int nf = 0; nf < 4; nf++) {
    const int c = n0 + wc * 64 + nf * 16 + lr;
    const float bval = bias[(e << 10) + c];
#pragma unroll
    for (int mf = 0; mf < 4; mf++) {
#pragma unroll
      for (int j = 0; j < 4; j++) {
        const int lrow2 = wr * 64 + mf * 16 + lk * 4 + j;
        if (lrow2 < mlim) {
          float v = acc[mf][nf][j] + bval;
          if (MODE == 0) {
            v = v > 0.f ? v : 0.f;
            hb[(size_t)(g0 + m0 + lrow2) * 1024 + c] = f32_to_bf16_bits(v);
          } else {
            int token = perm[g0 + m0 + lrow2];
            out[(size_t)token * 1024 + c] = v;
          }
        }
      }
    }
  }
}

// ---------- launch ----------
extern "C" void kernel_launch(void* const* d_in, const int* in_sizes, int n_in,
                              void* d_out, int out_size, void* d_ws, size_t ws_size,
                              hipStream_t stream) {
  const float* x = (const float*)d_in[0];
  const float* Wp = (const float*)d_in[1];
  const float* bp = (const float*)d_in[2];
  const float* W1 = (const float*)d_in[3];
  const float* b1 = (const float*)d_in[4];
  const float* W2 = (const float*)d_in[5];
  const float* b2 = (const float*)d_in[6];

  float* out = (float*)d_out;                      // [8192][1024]
  float* probs = out + (size_t)N_TOK * D_DIM;      // [8192][8]
  float* chosenF = probs + (size_t)N_TOK * E_NUM;  // [8192]

  char* ws = (char*)d_ws;
  int* chosen = (int*)(ws + 0);       // 32768 B
  int* counts = (int*)(ws + 32768);   // 32 B
  int* offsets = (int*)(ws + 32832);  // 64 B
  int* perm = (int*)(ws + 33024);     // 32768 B
  unsigned short* xb = (unsigned short*)(ws + 66048);                 // 16 MB
  unsigned short* Wt = (unsigned short*)(ws + 66048 + 16777216);      // 16 MB (W1t then W2t)
  unsigned short* hb = (unsigned short*)(ws + 66048 + 2 * 16777216);  // 16 MB
  // total ws use: 48.1 MB

  hipMemsetAsync(counts, 0, 32, stream);
  routing_kernel<<<N_TOK / 4, 256, 0, stream>>>(x, Wp, bp, probs, chosenF, chosen, counts, xb);
  scan_scatter_kernel<<<1, 1024, 0, stream>>>(counts, chosen, offsets, perm);
  transpose_cast_kernel<<<dim3(16, 16, 8), 256, 0, stream>>>(W1, Wt);
  moe_gemm_kernel<0><<<4096, 256, 0, stream>>>(xb, Wt, b1, offsets, perm, hb, nullptr);
  transpose_cast_kernel<<<dim3(16, 16, 8), 256, 0, stream>>>(W2, Wt);  // reuse Wt (W1t dead)
  moe_gemm_kernel<1><<<4096, 256, 0, stream>>>(hb, Wt, b2, offsets, perm, nullptr, out);
}

// Round 3
// 237.230 us; speedup vs baseline: 1.7721x; 1.1123x over previous
//
#include <hip/hip_runtime.h>
#include <stdint.h>

#define N_TOK 8192
#define D_DIM 1024
#define E_NUM 8

typedef float f32x4 __attribute__((ext_vector_type(4)));
typedef __bf16 bf16x8 __attribute__((ext_vector_type(8)));

__device__ __forceinline__ unsigned short f32_to_bf16_bits(float f) {
  union { float f; uint32_t u; } v; v.f = f;
  uint32_t u = v.u;
  uint32_t r = u + 0x7fffu + ((u >> 16) & 1u);  // RNE
  return (unsigned short)(r >> 16);
}

__device__ __forceinline__ void load_lds16(const void* g, void* l) {
  // async global->LDS, 16B/lane, dest = uniform base + lane*16
  __builtin_amdgcn_global_load_lds(
      (const __attribute__((address_space(1))) void*)g,
      (__attribute__((address_space(3))) void*)l, 16, 0, 0);
}

// ---------- shared 64x64 fp32->bf16 transpose tile (LDS-staged) ----------
__device__ __forceinline__ void transpose_tile(unsigned short (*T)[72],
                                               const float* __restrict__ S,
                                               unsigned short* __restrict__ O,
                                               int r0, int c0, int t) {
  const int rr = t >> 4;
  const int cc = (t & 15) * 4;
#pragma unroll
  for (int p = 0; p < 4; p++) {
    int r = p * 16 + rr;
    float4 v = *reinterpret_cast<const float4*>(S + (size_t)(r0 + r) * 1024 + c0 + cc);
    T[cc + 0][r] = f32_to_bf16_bits(v.x);
    T[cc + 1][r] = f32_to_bf16_bits(v.y);
    T[cc + 2][r] = f32_to_bf16_bits(v.z);
    T[cc + 3][r] = f32_to_bf16_bits(v.w);
  }
  __syncthreads();
#pragma unroll
  for (int p = 0; p < 4; p++) {
    int c = p * 16 + rr;
    ushort4 o = *reinterpret_cast<const ushort4*>(&T[c][cc]);
    *reinterpret_cast<ushort4*>(O + (size_t)(c0 + c) * 1024 + r0 + cc) = o;
  }
}

// ---------- Wp [1024][8] -> WpT [8][1024] (tiny; kills the routing gather) ----------
__global__ __launch_bounds__(256) void wpt_kernel(const float* __restrict__ Wp,
                                                  float* __restrict__ WpT) {
  int i = blockIdx.x * 256 + threadIdx.x;  // 8192 total
  int e = i >> 10, d = i & 1023;
  WpT[i] = Wp[(size_t)d * E_NUM + e];
}

// ---------- fused: routing (fp64 logits, coalesced WpT) + x->bf16 + W1 transpose ----
// bids 0..2047: routing, 4 tokens/block. bids 2048..4095: W1 64x64 transpose tiles.
// fp64 logits so argmax matches the np reference exactly (f32/bf16 flip tokens).
__global__ __launch_bounds__(256) void routing_w1t_kernel(
    const float* __restrict__ x, const float* __restrict__ WpT,
    const float* __restrict__ bp, float* __restrict__ probs_out,
    float* __restrict__ chosenF, int* __restrict__ chosen,
    int* __restrict__ counts, unsigned short* __restrict__ xb,
    const float* __restrict__ W1, unsigned short* __restrict__ W1t) {
  __shared__ __align__(16) unsigned short T[64][72];
  if (blockIdx.x >= 2048) {  // transpose role
    const int tb = blockIdx.x - 2048;
    const int e = tb >> 8, rc = tb & 255;
    transpose_tile(T, W1 + ((size_t)e << 20), W1t + ((size_t)e << 20),
                   (rc >> 4) * 64, (rc & 15) * 64, threadIdx.x);
    return;
  }
  const int wave = threadIdx.x >> 6;
  const int lane = threadIdx.x & 63;
  const int token = blockIdx.x * 4 + wave;
  const float* xr = x + (size_t)token * D_DIM;
  unsigned short* xbr = xb + (size_t)token * D_DIM;
  double acc[E_NUM];
#pragma unroll
  for (int e = 0; e < E_NUM; e++) acc[e] = 0.0;
#pragma unroll
  for (int it = 0; it < 4; it++) {
    const int d0 = it * 256 + lane * 4;
    float4 xv = *reinterpret_cast<const float4*>(xr + d0);
    ushort4 o;
    o.x = f32_to_bf16_bits(xv.x);
    o.y = f32_to_bf16_bits(xv.y);
    o.z = f32_to_bf16_bits(xv.z);
    o.w = f32_to_bf16_bits(xv.w);
    *reinterpret_cast<ushort4*>(xbr + d0) = o;
#pragma unroll
    for (int e = 0; e < E_NUM; e++) {
      float4 w = *reinterpret_cast<const float4*>(WpT + (e << 10) + d0);  // coalesced
      acc[e] += (double)xv.x * (double)w.x;
      acc[e] += (double)xv.y * (double)w.y;
      acc[e] += (double)xv.z * (double)w.z;
      acc[e] += (double)xv.w * (double)w.w;
    }
  }
#pragma unroll
  for (int e = 0; e < E_NUM; e++) {
#pragma unroll
    for (int off = 32; off > 0; off >>= 1) acc[e] += __shfl_xor(acc[e], off);
  }
  if (lane == 0) {
    double lg[E_NUM];
#pragma unroll
    for (int e = 0; e < E_NUM; e++) lg[e] = acc[e] + (double)bp[e];
    int best = 0;
    double bv = lg[0];
#pragma unroll
    for (int e = 1; e < E_NUM; e++)
      if (lg[e] > bv) { bv = lg[e]; best = e; }  // strict > == first-max (jnp.argmax)
    double s = 0.0, ex[E_NUM];
#pragma unroll
    for (int e = 0; e < E_NUM; e++) { ex[e] = exp(lg[e] - bv); s += ex[e]; }
    double inv = 1.0 / s;
#pragma unroll
    for (int e = 0; e < E_NUM; e++)
      probs_out[(size_t)token * E_NUM + e] = (float)(ex[e] * inv);
    chosenF[token] = (float)best;
    chosen[token] = best;
    atomicAdd(&counts[best], 1);
  }
}

// ---------- scan (8 experts) + scatter into per-expert groups, one block ----------
__global__ __launch_bounds__(1024) void scan_scatter_kernel(
    const int* __restrict__ counts, const int* __restrict__ chosen,
    int* __restrict__ offsets, int* __restrict__ perm) {
  __shared__ int curs[E_NUM];
  const int t = threadIdx.x;
  if (t == 0) {
    int off = 0;
    for (int e = 0; e < E_NUM; e++) { offsets[e] = off; curs[e] = off; off += counts[e]; }
    offsets[E_NUM] = off;
  }
  __syncthreads();
  for (int n = t; n < N_TOK; n += 1024) {
    int e = chosen[n];
    int p = atomicAdd(&curs[e], 1);  // in-group order irrelevant
    perm[p] = n;
  }
}

// ---------- standalone per-expert transpose (sequential fallback path) ----------
__global__ __launch_bounds__(256) void transpose_cast_kernel(
    const float* __restrict__ src, unsigned short* __restrict__ dst) {
  __shared__ __align__(16) unsigned short T[64][72];
  const int e = blockIdx.z;
  transpose_tile(T, src + ((size_t)e << 20), dst + ((size_t)e << 20),
                 blockIdx.y * 64, blockIdx.x * 64, threadIdx.x);
}

// ---------- grouped GEMM: 128x128 tile, BK=64, 4 waves, m97-structure ----------
// global_load_lds (16B) -> linear LDS, single-buffered, 2 barriers per K-step.
// gemm role: bid<gemm_blocks; e = bid&7 (expert-per-XCD L2 locality),
// slot = bid>>3, m-tile = slot>>3, n-tile = slot&7.
// bids >= gemm_blocks: W2 transpose tiles (fills CUs idle under gemm early-exit).
// MODE 0: h = relu(x[perm] @ W1t^T + b1) -> hb (bf16, group-compacted)
// MODE 1: out[perm] = hb @ W2t^T + b2    (fp32 scatter)
template <int MODE>
__global__ __launch_bounds__(256) void moe_gemm_kernel(
    const unsigned short* __restrict__ Abase,  // xb (MODE0) / hb (MODE1)
    const unsigned short* __restrict__ Wt,     // bf16 [E][1024(n)][1024(k)]
    const float* __restrict__ bias,            // [E][1024]
    const int* __restrict__ offsets, const int* __restrict__ perm,
    unsigned short* __restrict__ hb, float* __restrict__ out,
    const float* __restrict__ tsrc, unsigned short* __restrict__ tdst,
    int gemm_blocks) {
  __shared__ __align__(16) unsigned short As[128 * 64];
  __shared__ __align__(16) unsigned short Bs[128 * 64];

  if ((int)blockIdx.x >= gemm_blocks) {  // transpose role (MODE 0 overlap path)
    const int tb = blockIdx.x - gemm_blocks;
    const int e = tb >> 8, rc = tb & 255;
    auto T = reinterpret_cast<unsigned short(*)[72]>(As);
    transpose_tile(T, tsrc + ((size_t)e << 20), tdst + ((size_t)e << 20),
                   (rc >> 4) * 64, (rc & 15) * 64, threadIdx.x);
    return;
  }

  const int e = blockIdx.x & 7;
  const int slot = blockIdx.x >> 3;
  const int g0 = offsets[e];
  const int m_count = offsets[e + 1] - g0;
  const int m0 = (slot >> 3) * 128;
  if (m0 >= m_count) return;  // uniform early-exit, before any barrier
  const int n0 = (slot & 7) * 128;

  const int tid = threadIdx.x;
  const int wid = tid >> 6, lane = tid & 63;
  const int lrow = lane >> 3;   // 0..7: row within the wave's 8-row stripe
  const int lchunk = lane & 7;  // 16B chunk within the 128B k-row

  const unsigned short* ga[4];
  const unsigned short* gb[4];
  unsigned short* la[4];
  unsigned short* lb[4];
  const unsigned short* WtE = Wt + ((size_t)e << 20);
#pragma unroll
  for (int t = 0; t < 4; t++) {
    const int rbase = t * 32 + wid * 8;  // wave-uniform
    const int r = rbase + lrow;          // 0..127
    int gr = g0 + m0 + r;
    if (gr > N_TOK - 1) gr = N_TOK - 1;  // clamp partial m-tiles
    const int arow = (MODE == 0) ? perm[gr] : gr;
    ga[t] = Abase + (size_t)arow * 1024 + lchunk * 8;
    gb[t] = WtE + (size_t)(n0 + r) * 1024 + lchunk * 8;
    la[t] = &As[rbase * 64];  // uniform per wave (required)
    lb[t] = &Bs[rbase * 64];
  }

  f32x4 acc[4][4];
  const f32x4 zero4 = {0.f, 0.f, 0.f, 0.f};
#pragma unroll
  for (int i = 0; i < 4; i++)
#pragma unroll
    for (int j = 0; j < 4; j++) acc[i][j] = zero4;

  const int wr = wid >> 1, wc = wid & 1;
  const int lr = lane & 15, lk = lane >> 4;

  auto stage = [&]() {
#pragma unroll
    for (int t = 0; t < 4; t++) {
      load_lds16(ga[t], la[t]);
      load_lds16(gb[t], lb[t]);
      ga[t] += 64;
      gb[t] += 64;
    }
  };
  auto compute = [&]() {
#pragma unroll
    for (int kk = 0; kk < 64; kk += 32) {
      bf16x8 af[4], bfr[4];
#pragma unroll
      for (int mf = 0; mf < 4; mf++)
        af[mf] = *reinterpret_cast<const bf16x8*>(
            &As[(wr * 64 + mf * 16 + lr) * 64 + kk + lk * 8]);
#pragma unroll
      for (int nf = 0; nf < 4; nf++)
        bfr[nf] = *reinterpret_cast<const bf16x8*>(
            &Bs[(wc * 64 + nf * 16 + lr) * 64 + kk + lk * 8]);
#pragma unroll
      for (int mf = 0; mf < 4; mf++)
#pragma unroll
        for (int nf = 0; nf < 4; nf++)
          acc[mf][nf] = __builtin_amdgcn_mfma_f32_16x16x32_bf16(
              af[mf], bfr[nf], acc[mf][nf], 0, 0, 0);
    }
  };

  stage();
  __syncthreads();  // vmcnt(0) drain + barrier: tile 0 ready
  for (int kt = 0; kt < 16; kt++) {
    compute();
    if (kt < 15) {
      __syncthreads();  // all waves done reading
      stage();
      __syncthreads();  // next tile ready
    }
  }

  // epilogue: C/D layout col=lane&15, row=(lane>>4)*4+reg [m89]
  const int mlim = m_count - m0;
#pragma unroll
  for (int nf = 0; nf < 4; nf++) {
    const int c = n0 + wc * 64 + nf * 16 + lr;
    const float bval = bias[(e << 10) + c];
#pragma unroll
    for (int mf = 0; mf < 4; mf++) {
#pragma unroll
      for (int j = 0; j < 4; j++) {
        const int lrow2 = wr * 64 + mf * 16 + lk * 4 + j;
        if (lrow2 < mlim) {
          float v = acc[mf][nf][j] + bval;
          if (MODE == 0) {
            v = v > 0.f ? v : 0.f;
            hb[(size_t)(g0 + m0 + lrow2) * 1024 + c] = f32_to_bf16_bits(v);
          } else {
            int token = perm[g0 + m0 + lrow2];
            out[(size_t)token * 1024 + c] = v;
          }
        }
      }
    }
  }
}

// ---------- launch ----------
extern "C" void kernel_launch(void* const* d_in, const int* in_sizes, int n_in,
                              void* d_out, int out_size, void* d_ws, size_t ws_size,
                              hipStream_t stream) {
  const float* x = (const float*)d_in[0];
  const float* Wp = (const float*)d_in[1];
  const float* bp = (const float*)d_in[2];
  const float* W1 = (const float*)d_in[3];
  const float* b1 = (const float*)d_in[4];
  const float* W2 = (const float*)d_in[5];
  const float* b2 = (const float*)d_in[6];

  float* out = (float*)d_out;                      // [8192][1024]
  float* probs = out + (size_t)N_TOK * D_DIM;      // [8192][8]
  float* chosenF = probs + (size_t)N_TOK * E_NUM;  // [8192]

  char* ws = (char*)d_ws;
  int* chosen = (int*)(ws + 0);         // 32 KB
  int* perm = (int*)(ws + 32768);       // 32 KB
  float* WpT = (float*)(ws + 65536);    // 32 KB
  int* counts = (int*)(ws + 98304);     // 32 B
  int* offsets = (int*)(ws + 98368);    // 64 B
  const size_t MB16 = 16777216;
  unsigned short* xb = (unsigned short*)(ws + 131072);          // 16 MB
  unsigned short* Wt1 = (unsigned short*)(ws + 131072 + MB16);  // 16 MB
  // overlap path: Wt2 separate (GEMM1 reads Wt1 while W2T is written);
  // sequential fallback: Wt2 aliases Wt1 (written after GEMM1 completes).
  const bool overlap = ws_size >= 131072 + 4 * MB16;
  unsigned short* Wt2 = (unsigned short*)(ws + 131072 + (overlap ? 2 : 1) * MB16);
  unsigned short* hb = (unsigned short*)(ws + 131072 + (overlap ? 3 : 2) * MB16);

  hipMemsetAsync(counts, 0, 32, stream);
  wpt_kernel<<<32, 256, 0, stream>>>(Wp, WpT);
  routing_w1t_kernel<<<4096, 256, 0, stream>>>(x, WpT, bp, probs, chosenF, chosen,
                                               counts, xb, W1, Wt1);
  scan_scatter_kernel<<<1, 1024, 0, stream>>>(counts, chosen, offsets, perm);
  if (overlap) {
    moe_gemm_kernel<0><<<4096 + 2048, 256, 0, stream>>>(
        xb, Wt1, b1, offsets, perm, hb, nullptr, W2, Wt2, 4096);
  } else {
    moe_gemm_kernel<0><<<4096, 256, 0, stream>>>(
        xb, Wt1, b1, offsets, perm, hb, nullptr, nullptr, nullptr, 4096);
    transpose_cast_kernel<<<dim3(16, 16, 8), 256, 0, stream>>>(W2, Wt2);
  }
  moe_gemm_kernel<1><<<4096, 256, 0, stream>>>(
      hb, Wt2, b2, offsets, perm, nullptr, out, nullptr, nullptr, 4096);
}

// Round 4
// 129.762 us; speedup vs baseline: 3.2398x; 1.8282x over previous
//
#include <hip/hip_runtime.h>
#include <stdint.h>

#define N_TOK 8192
#define D_DIM 1024
#define E_NUM 8

typedef float f32x4 __attribute__((ext_vector_type(4)));
typedef __bf16 bf16x8 __attribute__((ext_vector_type(8)));

__device__ __forceinline__ unsigned short f32_to_bf16_bits(float f) {
  union { float f; uint32_t u; } v; v.f = f;
  uint32_t u = v.u;
  uint32_t r = u + 0x7fffu + ((u >> 16) & 1u);  // RNE
  return (unsigned short)(r >> 16);
}

__device__ __forceinline__ void load_lds16(const void* g, void* l) {
  // async global->LDS, 16B/lane, dest = uniform base + lane*16
  __builtin_amdgcn_global_load_lds(
      (const __attribute__((address_space(1))) void*)g,
      (__attribute__((address_space(3))) void*)l, 16, 0, 0);
}

// ---------- shared 64x64 fp32->bf16 transpose tile (LDS-staged) ----------
__device__ __forceinline__ void transpose_tile(unsigned short (*T)[72],
                                               const float* __restrict__ S,
                                               unsigned short* __restrict__ O,
                                               int r0, int c0, int t) {
  const int rr = t >> 4;
  const int cc = (t & 15) * 4;
#pragma unroll
  for (int p = 0; p < 4; p++) {
    int r = p * 16 + rr;
    float4 v = *reinterpret_cast<const float4*>(S + (size_t)(r0 + r) * 1024 + c0 + cc);
    T[cc + 0][r] = f32_to_bf16_bits(v.x);
    T[cc + 1][r] = f32_to_bf16_bits(v.y);
    T[cc + 2][r] = f32_to_bf16_bits(v.z);
    T[cc + 3][r] = f32_to_bf16_bits(v.w);
  }
  __syncthreads();
#pragma unroll
  for (int p = 0; p < 4; p++) {
    int c = p * 16 + rr;
    ushort4 o = *reinterpret_cast<const ushort4*>(&T[c][cc]);
    *reinterpret_cast<ushort4*>(O + (size_t)(c0 + c) * 1024 + r0 + cc) = o;
  }
}

// ---------- Wp [1024][8] -> WpT [8][1024] ----------
__global__ __launch_bounds__(256) void wpt_kernel(const float* __restrict__ Wp,
                                                  float* __restrict__ WpT) {
  int i = blockIdx.x * 256 + threadIdx.x;  // 8192 total
  int e = i >> 10, d = i & 1023;
  WpT[i] = Wp[(size_t)d * E_NUM + e];
}

// ---------- fused: routing (fp64 logits) + x->bf16 + W1 transpose ----------
// bids 0..2047: routing, 4 tokens/block. bids 2048..4095: W1 64x64 transpose tiles.
// fp64 logits so argmax matches the np reference exactly.
// NO global atomics here (R3 post-mortem: 8192 same-line atomicAdds serialized
// ~60-70us of wave-retire tail). Histogram moved to scan_scatter (LDS atomics).
__global__ __launch_bounds__(256) void routing_w1t_kernel(
    const float* __restrict__ x, const float* __restrict__ WpT,
    const float* __restrict__ bp, float* __restrict__ probs_out,
    float* __restrict__ chosenF, int* __restrict__ chosen,
    unsigned short* __restrict__ xb,
    const float* __restrict__ W1, unsigned short* __restrict__ W1t) {
  __shared__ __align__(16) unsigned short T[64][72];
  __shared__ __align__(16) float pbuf[4][8];
  if (blockIdx.x >= 2048) {  // transpose role
    const int tb = blockIdx.x - 2048;
    const int e = tb >> 8, rc = tb & 255;
    transpose_tile(T, W1 + ((size_t)e << 20), W1t + ((size_t)e << 20),
                   (rc >> 4) * 64, (rc & 15) * 64, threadIdx.x);
    return;
  }
  const int wave = threadIdx.x >> 6;
  const int lane = threadIdx.x & 63;
  const int token = blockIdx.x * 4 + wave;
  const float* xr = x + (size_t)token * D_DIM;
  unsigned short* xbr = xb + (size_t)token * D_DIM;
  double acc[E_NUM];
#pragma unroll
  for (int e = 0; e < E_NUM; e++) acc[e] = 0.0;
#pragma unroll
  for (int it = 0; it < 4; it++) {
    const int d0 = it * 256 + lane * 4;
    float4 xv = *reinterpret_cast<const float4*>(xr + d0);
    ushort4 o;
    o.x = f32_to_bf16_bits(xv.x);
    o.y = f32_to_bf16_bits(xv.y);
    o.z = f32_to_bf16_bits(xv.z);
    o.w = f32_to_bf16_bits(xv.w);
    *reinterpret_cast<ushort4*>(xbr + d0) = o;
#pragma unroll
    for (int e = 0; e < E_NUM; e++) {
      float4 w = *reinterpret_cast<const float4*>(WpT + (e << 10) + d0);  // coalesced
      acc[e] += (double)xv.x * (double)w.x;
      acc[e] += (double)xv.y * (double)w.y;
      acc[e] += (double)xv.z * (double)w.z;
      acc[e] += (double)xv.w * (double)w.w;
    }
  }
#pragma unroll
  for (int e = 0; e < E_NUM; e++) {
#pragma unroll
    for (int off = 32; off > 0; off >>= 1) acc[e] += __shfl_xor(acc[e], off);
  }
  if (lane == 0) {
    double lg[E_NUM];
#pragma unroll
    for (int e = 0; e < E_NUM; e++) lg[e] = acc[e] + (double)bp[e];
    int best = 0;
    double bv = lg[0];
#pragma unroll
    for (int e = 1; e < E_NUM; e++)
      if (lg[e] > bv) { bv = lg[e]; best = e; }  // strict > == first-max (jnp.argmax)
    double s = 0.0, ex[E_NUM];
#pragma unroll
    for (int e = 0; e < E_NUM; e++) { ex[e] = exp(lg[e] - bv); s += ex[e]; }
    double inv = 1.0 / s;
#pragma unroll
    for (int e = 0; e < E_NUM; e++) pbuf[wave][e] = (float)(ex[e] * inv);
    chosenF[token] = (float)best;
    chosen[token] = best;
  }
  __syncthreads();
  if (threadIdx.x < 8) {  // coalesced 128B probs store per block
    float4 v = *reinterpret_cast<const float4*>(
        &pbuf[threadIdx.x >> 1][(threadIdx.x & 1) * 4]);
    reinterpret_cast<float4*>(probs_out + (size_t)blockIdx.x * 32)[threadIdx.x] = v;
  }
}

// ---------- histogram + scan + scatter, one block, LDS atomics only ----------
__global__ __launch_bounds__(1024) void scan_scatter_kernel(
    const int* __restrict__ chosen, int* __restrict__ offsets,
    int* __restrict__ perm) {
  __shared__ int hist[E_NUM];
  __shared__ int curs[E_NUM];
  const int t = threadIdx.x;
  if (t < E_NUM) hist[t] = 0;
  __syncthreads();
  for (int n = t; n < N_TOK; n += 1024) atomicAdd(&hist[chosen[n]], 1);
  __syncthreads();
  if (t == 0) {
    int off = 0;
    for (int e = 0; e < E_NUM; e++) { offsets[e] = off; curs[e] = off; off += hist[e]; }
    offsets[E_NUM] = off;
  }
  __syncthreads();
  for (int n = t; n < N_TOK; n += 1024) {
    int e = chosen[n];
    int p = atomicAdd(&curs[e], 1);  // in-group order irrelevant
    perm[p] = n;
  }
}

// ---------- standalone per-expert transpose (sequential fallback path) ----------
__global__ __launch_bounds__(256) void transpose_cast_kernel(
    const float* __restrict__ src, unsigned short* __restrict__ dst) {
  __shared__ __align__(16) unsigned short T[64][72];
  const int e = blockIdx.z;
  transpose_tile(T, src + ((size_t)e << 20), dst + ((size_t)e << 20),
                 blockIdx.y * 64, blockIdx.x * 64, threadIdx.x);
}

// ---------- grouped GEMM: 128x64 tile, BK=64, 4 waves, m97-structure ----------
// global_load_lds (16B) -> linear LDS, single-buffered, 2 barriers per K-step.
// BN=64 (R4): doubles active blocks to ~1024 = 4/CU (was 2/CU at BN=128).
// Slots cover the WORST-CASE routing skew: 64 m-tiles/expert (8192 tokens);
// inactive blocks exit before any barrier. e = bid&7 (expert-per-XCD L2).
// bids >= gemm_blocks: W2 transpose tiles (fill idle CUs during GEMM1).
// MODE 0: h = relu(x[perm] @ W1t^T + b1) -> hb (bf16, group-compacted)
// MODE 1: out[perm] = hb @ W2t^T + b2    (fp32 scatter)
template <int MODE>
__global__ __launch_bounds__(256) void moe_gemm_kernel(
    const unsigned short* __restrict__ Abase,  // xb (MODE0) / hb (MODE1)
    const unsigned short* __restrict__ Wt,     // bf16 [E][1024(n)][1024(k)]
    const float* __restrict__ bias,            // [E][1024]
    const int* __restrict__ offsets, const int* __restrict__ perm,
    unsigned short* __restrict__ hb, float* __restrict__ out,
    const float* __restrict__ tsrc, unsigned short* __restrict__ tdst,
    int gemm_blocks) {
  __shared__ __align__(16) unsigned short As[128 * 64];  // 16 KB
  __shared__ __align__(16) unsigned short Bs[64 * 64];   // 8 KB

  if ((int)blockIdx.x >= gemm_blocks) {  // transpose role (MODE 0 overlap path)
    const int tb = blockIdx.x - gemm_blocks;
    const int e = tb >> 8, rc = tb & 255;
    auto T = reinterpret_cast<unsigned short(*)[72]>(As);
    transpose_tile(T, tsrc + ((size_t)e << 20), tdst + ((size_t)e << 20),
                   (rc >> 4) * 64, (rc & 15) * 64, threadIdx.x);
    return;
  }

  const int e = blockIdx.x & 7;
  const int slot = blockIdx.x >> 3;   // 0..1023 per expert
  const int g0 = offsets[e];
  const int m_count = offsets[e + 1] - g0;
  const int m0 = (slot >> 4) * 128;   // 64 m-tiles: covers any skew
  if (m0 >= m_count) return;          // uniform early-exit, before any barrier
  const int n0 = (slot & 15) * 64;

  const int tid = threadIdx.x;
  const int wid = tid >> 6, lane = tid & 63;
  const int lrow = lane >> 3;   // 0..7: row within the wave's 8-row stripe
  const int lchunk = lane & 7;  // 16B chunk within the 128B k-row

  const unsigned short* ga[4];
  const unsigned short* gb[2];
  unsigned short* la[4];
  unsigned short* lb[2];
  const unsigned short* WtE = Wt + ((size_t)e << 20);
#pragma unroll
  for (int t = 0; t < 4; t++) {
    const int rbase = t * 32 + wid * 8;  // wave-uniform
    const int r = rbase + lrow;          // 0..127
    int gr = g0 + m0 + r;
    if (gr > N_TOK - 1) gr = N_TOK - 1;  // clamp partial m-tiles
    const int arow = (MODE == 0) ? perm[gr] : gr;
    ga[t] = Abase + (size_t)arow * 1024 + lchunk * 8;
    la[t] = &As[rbase * 64];  // uniform per wave (required)
  }
#pragma unroll
  for (int t = 0; t < 2; t++) {
    const int rbase = t * 32 + wid * 8;
    const int r = rbase + lrow;          // 0..63
    gb[t] = WtE + (size_t)(n0 + r) * 1024 + lchunk * 8;
    lb[t] = &Bs[rbase * 64];
  }

  f32x4 acc[4][2];
  const f32x4 zero4 = {0.f, 0.f, 0.f, 0.f};
#pragma unroll
  for (int i = 0; i < 4; i++)
#pragma unroll
    for (int j = 0; j < 2; j++) acc[i][j] = zero4;

  const int wr = wid >> 1, wc = wid & 1;  // wave tile: 64 rows x 32 cols
  const int lr = lane & 15, lk = lane >> 4;

  auto stage = [&]() {
#pragma unroll
    for (int t = 0; t < 4; t++) {
      load_lds16(ga[t], la[t]);
      ga[t] += 64;
    }
#pragma unroll
    for (int t = 0; t < 2; t++) {
      load_lds16(gb[t], lb[t]);
      gb[t] += 64;
    }
  };
  auto compute = [&]() {
#pragma unroll
    for (int kk = 0; kk < 64; kk += 32) {
      bf16x8 af[4], bfr[2];
#pragma unroll
      for (int mf = 0; mf < 4; mf++)
        af[mf] = *reinterpret_cast<const bf16x8*>(
            &As[(wr * 64 + mf * 16 + lr) * 64 + kk + lk * 8]);
#pragma unroll
      for (int nf = 0; nf < 2; nf++)
        bfr[nf] = *reinterpret_cast<const bf16x8*>(
            &Bs[(wc * 32 + nf * 16 + lr) * 64 + kk + lk * 8]);
#pragma unroll
      for (int mf = 0; mf < 4; mf++)
#pragma unroll
        for (int nf = 0; nf < 2; nf++)
          acc[mf][nf] = __builtin_amdgcn_mfma_f32_16x16x32_bf16(
              af[mf], bfr[nf], acc[mf][nf], 0, 0, 0);
    }
  };

  stage();
  __syncthreads();  // vmcnt(0) drain + barrier: tile 0 ready
  for (int kt = 0; kt < 16; kt++) {
    compute();
    if (kt < 15) {
      __syncthreads();  // all waves done reading
      stage();
      __syncthreads();  // next tile ready
    }
  }

  // epilogue: C/D layout col=lane&15, row=(lane>>4)*4+reg [m89]
  const int mlim = m_count - m0;
#pragma unroll
  for (int nf = 0; nf < 2; nf++) {
    const int c = n0 + wc * 32 + nf * 16 + lr;
    const float bval = bias[(e << 10) + c];
#pragma unroll
    for (int mf = 0; mf < 4; mf++) {
#pragma unroll
      for (int j = 0; j < 4; j++) {
        const int lrow2 = wr * 64 + mf * 16 + lk * 4 + j;
        if (lrow2 < mlim) {
          float v = acc[mf][nf][j] + bval;
          if (MODE == 0) {
            v = v > 0.f ? v : 0.f;
            hb[(size_t)(g0 + m0 + lrow2) * 1024 + c] = f32_to_bf16_bits(v);
          } else {
            int token = perm[g0 + m0 + lrow2];
            out[(size_t)token * 1024 + c] = v;
          }
        }
      }
    }
  }
}

// ---------- launch ----------
extern "C" void kernel_launch(void* const* d_in, const int* in_sizes, int n_in,
                              void* d_out, int out_size, void* d_ws, size_t ws_size,
                              hipStream_t stream) {
  const float* x = (const float*)d_in[0];
  const float* Wp = (const float*)d_in[1];
  const float* bp = (const float*)d_in[2];
  const float* W1 = (const float*)d_in[3];
  const float* b1 = (const float*)d_in[4];
  const float* W2 = (const float*)d_in[5];
  const float* b2 = (const float*)d_in[6];

  float* out = (float*)d_out;                      // [8192][1024]
  float* probs = out + (size_t)N_TOK * D_DIM;      // [8192][8]
  float* chosenF = probs + (size_t)N_TOK * E_NUM;  // [8192]

  char* ws = (char*)d_ws;
  int* chosen = (int*)(ws + 0);       // 32 KB
  int* perm = (int*)(ws + 32768);     // 32 KB
  float* WpT = (float*)(ws + 65536);  // 32 KB
  int* offsets = (int*)(ws + 98304);  // 64 B
  const size_t MB16 = 16777216;
  unsigned short* xb = (unsigned short*)(ws + 131072);          // 16 MB
  unsigned short* Wt1 = (unsigned short*)(ws + 131072 + MB16);  // 16 MB
  // overlap path: Wt2 separate (GEMM1 reads Wt1 while W2T is written);
  // sequential fallback: Wt2 aliases Wt1 (written after GEMM1 completes).
  const bool overlap = ws_size >= 131072 + 4 * MB16;
  unsigned short* Wt2 = (unsigned short*)(ws + 131072 + (overlap ? 2 : 1) * MB16);
  unsigned short* hb = (unsigned short*)(ws + 131072 + (overlap ? 3 : 2) * MB16);

  const int GEMM_BLOCKS = E_NUM * 64 * 16;  // 8192: worst-case m coverage x 16 n-tiles

  wpt_kernel<<<32, 256, 0, stream>>>(Wp, WpT);
  routing_w1t_kernel<<<4096, 256, 0, stream>>>(x, WpT, bp, probs, chosenF, chosen,
                                               xb, W1, Wt1);
  scan_scatter_kernel<<<1, 1024, 0, stream>>>(chosen, offsets, perm);
  if (overlap) {
    moe_gemm_kernel<0><<<GEMM_BLOCKS + 2048, 256, 0, stream>>>(
        xb, Wt1, b1, offsets, perm, hb, nullptr, W2, Wt2, GEMM_BLOCKS);
  } else {
    moe_gemm_kernel<0><<<GEMM_BLOCKS, 256, 0, stream>>>(
        xb, Wt1, b1, offsets, perm, hb, nullptr, nullptr, nullptr, GEMM_BLOCKS);
    transpose_cast_kernel<<<dim3(16, 16, 8), 256, 0, stream>>>(W2, Wt2);
  }
  moe_gemm_kernel<1><<<GEMM_BLOCKS, 256, 0, stream>>>(
      hb, Wt2, b2, offsets, perm, nullptr, out, nullptr, nullptr, GEMM_BLOCKS);
}

// Round 5
// 129.288 us; speedup vs baseline: 3.2516x; 1.0037x over previous
//
#include <hip/hip_runtime.h>
#include <stdint.h>

#define N_TOK 8192
#define D_DIM 1024
#define E_NUM 8

typedef float f32x4 __attribute__((ext_vector_type(4)));
typedef __bf16 bf16x8 __attribute__((ext_vector_type(8)));

__device__ __forceinline__ unsigned short f32_to_bf16_bits(float f) {
  union { float f; uint32_t u; } v; v.f = f;
  uint32_t u = v.u;
  uint32_t r = u + 0x7fffu + ((u >> 16) & 1u);  // RNE
  return (unsigned short)(r >> 16);
}

__device__ __forceinline__ void load_lds16(const void* g, void* l) {
  // async global->LDS, 16B/lane, dest = uniform base + lane*16
  __builtin_amdgcn_global_load_lds(
      (const __attribute__((address_space(1))) void*)g,
      (__attribute__((address_space(3))) void*)l, 16, 0, 0);
}

// ---------- shared 64x64 fp32->bf16 transpose tile (LDS-staged) ----------
__device__ __forceinline__ void transpose_tile(unsigned short (*T)[72],
                                               const float* __restrict__ S,
                                               unsigned short* __restrict__ O,
                                               int r0, int c0, int t) {
  const int rr = t >> 4;
  const int cc = (t & 15) * 4;
#pragma unroll
  for (int p = 0; p < 4; p++) {
    int r = p * 16 + rr;
    float4 v = *reinterpret_cast<const float4*>(S + (size_t)(r0 + r) * 1024 + c0 + cc);
    T[cc + 0][r] = f32_to_bf16_bits(v.x);
    T[cc + 1][r] = f32_to_bf16_bits(v.y);
    T[cc + 2][r] = f32_to_bf16_bits(v.z);
    T[cc + 3][r] = f32_to_bf16_bits(v.w);
  }
  __syncthreads();
#pragma unroll
  for (int p = 0; p < 4; p++) {
    int c = p * 16 + rr;
    ushort4 o = *reinterpret_cast<const ushort4*>(&T[c][cc]);
    *reinterpret_cast<ushort4*>(O + (size_t)(c0 + c) * 1024 + r0 + cc) = o;
  }
}

// ---------- Wp [1024][8] -> WpT [8][1024] ----------
__global__ __launch_bounds__(256) void wpt_kernel(const float* __restrict__ Wp,
                                                  float* __restrict__ WpT) {
  int i = blockIdx.x * 256 + threadIdx.x;  // 8192 total
  int e = i >> 10, d = i & 1023;
  WpT[i] = Wp[(size_t)d * E_NUM + e];
}

// ---------- fused: routing (fp64 logits) + x->bf16 + W1 transpose ----------
// bids 0..2047: routing, 4 tokens/block. bids 2048..4095: W1 64x64 transpose tiles.
// fp64 logits so argmax matches the np reference exactly.
// NO global atomics (R3: 8192 same-line atomicAdds serialized ~70us of tail).
__global__ __launch_bounds__(256) void routing_w1t_kernel(
    const float* __restrict__ x, const float* __restrict__ WpT,
    const float* __restrict__ bp, float* __restrict__ probs_out,
    float* __restrict__ chosenF, int* __restrict__ chosen,
    unsigned short* __restrict__ xb,
    const float* __restrict__ W1, unsigned short* __restrict__ W1t) {
  __shared__ __align__(16) unsigned short T[64][72];
  __shared__ __align__(16) float pbuf[4][8];
  if (blockIdx.x >= 2048) {  // transpose role
    const int tb = blockIdx.x - 2048;
    const int e = tb >> 8, rc = tb & 255;
    transpose_tile(T, W1 + ((size_t)e << 20), W1t + ((size_t)e << 20),
                   (rc >> 4) * 64, (rc & 15) * 64, threadIdx.x);
    return;
  }
  const int wave = threadIdx.x >> 6;
  const int lane = threadIdx.x & 63;
  const int token = blockIdx.x * 4 + wave;
  const float* xr = x + (size_t)token * D_DIM;
  unsigned short* xbr = xb + (size_t)token * D_DIM;
  double acc[E_NUM];
#pragma unroll
  for (int e = 0; e < E_NUM; e++) acc[e] = 0.0;
#pragma unroll
  for (int it = 0; it < 4; it++) {
    const int d0 = it * 256 + lane * 4;
    float4 xv = *reinterpret_cast<const float4*>(xr + d0);
    ushort4 o;
    o.x = f32_to_bf16_bits(xv.x);
    o.y = f32_to_bf16_bits(xv.y);
    o.z = f32_to_bf16_bits(xv.z);
    o.w = f32_to_bf16_bits(xv.w);
    *reinterpret_cast<ushort4*>(xbr + d0) = o;
#pragma unroll
    for (int e = 0; e < E_NUM; e++) {
      float4 w = *reinterpret_cast<const float4*>(WpT + (e << 10) + d0);  // coalesced
      acc[e] += (double)xv.x * (double)w.x;
      acc[e] += (double)xv.y * (double)w.y;
      acc[e] += (double)xv.z * (double)w.z;
      acc[e] += (double)xv.w * (double)w.w;
    }
  }
#pragma unroll
  for (int e = 0; e < E_NUM; e++) {
#pragma unroll
    for (int off = 32; off > 0; off >>= 1) acc[e] += __shfl_xor(acc[e], off);
  }
  if (lane == 0) {
    double lg[E_NUM];
#pragma unroll
    for (int e = 0; e < E_NUM; e++) lg[e] = acc[e] + (double)bp[e];
    int best = 0;
    double bv = lg[0];
#pragma unroll
    for (int e = 1; e < E_NUM; e++)
      if (lg[e] > bv) { bv = lg[e]; best = e; }  // strict > == first-max (jnp.argmax)
    double s = 0.0, ex[E_NUM];
#pragma unroll
    for (int e = 0; e < E_NUM; e++) { ex[e] = exp(lg[e] - bv); s += ex[e]; }
    double inv = 1.0 / s;
#pragma unroll
    for (int e = 0; e < E_NUM; e++) pbuf[wave][e] = (float)(ex[e] * inv);
    chosenF[token] = (float)best;
    chosen[token] = best;
  }
  __syncthreads();
  if (threadIdx.x < 8) {  // coalesced 128B probs store per block
    float4 v = *reinterpret_cast<const float4*>(
        &pbuf[threadIdx.x >> 1][(threadIdx.x & 1) * 4]);
    reinterpret_cast<float4*>(probs_out + (size_t)blockIdx.x * 32)[threadIdx.x] = v;
  }
}

// ---------- histogram + scan + scatter, one block, LDS atomics only ----------
__global__ __launch_bounds__(1024) void scan_scatter_kernel(
    const int* __restrict__ chosen, int* __restrict__ offsets,
    int* __restrict__ perm) {
  __shared__ int hist[E_NUM];
  __shared__ int curs[E_NUM];
  const int t = threadIdx.x;
  if (t < E_NUM) hist[t] = 0;
  __syncthreads();
  for (int n = t; n < N_TOK; n += 1024) atomicAdd(&hist[chosen[n]], 1);
  __syncthreads();
  if (t == 0) {
    int off = 0;
    for (int e = 0; e < E_NUM; e++) { offsets[e] = off; curs[e] = off; off += hist[e]; }
    offsets[E_NUM] = off;
  }
  __syncthreads();
  for (int n = t; n < N_TOK; n += 1024) {
    int e = chosen[n];
    int p = atomicAdd(&curs[e], 1);  // in-group order irrelevant
    perm[p] = n;
  }
}

// ---------- standalone per-expert transpose (sequential fallback path) ----------
__global__ __launch_bounds__(256) void transpose_cast_kernel(
    const float* __restrict__ src, unsigned short* __restrict__ dst) {
  __shared__ __align__(16) unsigned short T[64][72];
  const int e = blockIdx.z;
  transpose_tile(T, src + ((size_t)e << 20), dst + ((size_t)e << 20),
                 blockIdx.y * 64, blockIdx.x * 64, threadIdx.x);
}

// ---------- grouped GEMM: 128x128 tile, BK=64, 4 waves ----------
// R5: BN back to 128 (acc 4x4 -> 2.0 MFMA/ds_read) + T2 XOR swizzle applied
// the only legal way with global_load_lds (rule #21 both-sides-or-neither):
//   - LDS dest stays LINEAR (HW requires base + lane*16)
//   - global SOURCE chunk per lane is lchunk ^ lrow  -> LDS[row][c] holds
//     global chunk (c ^ (row&7))
//   - ds_read uses chunk (cg ^ (row&7))  -> lanes 0-15 spread over 8 bank
//     groups, 2-way max = free (m136)
// R4 counters: 14.6 extra conflict-cyc per ds_read (16-way signature), LDS
// ~61% of wall. Predict conflicts -> ~0, GEMM 55 -> ~25us.
// MODE 0: h = relu(x[perm] @ W1t^T + b1) -> hb   MODE 1: out[perm] = hb @ W2t^T + b2
template <int MODE>
__global__ __launch_bounds__(256) void moe_gemm_kernel(
    const unsigned short* __restrict__ Abase,  // xb (MODE0) / hb (MODE1)
    const unsigned short* __restrict__ Wt,     // bf16 [E][1024(n)][1024(k)]
    const float* __restrict__ bias,            // [E][1024]
    const int* __restrict__ offsets, const int* __restrict__ perm,
    unsigned short* __restrict__ hb, float* __restrict__ out,
    const float* __restrict__ tsrc, unsigned short* __restrict__ tdst,
    int gemm_blocks) {
  __shared__ __align__(16) unsigned short As[128 * 64];  // 16 KB
  __shared__ __align__(16) unsigned short Bs[128 * 64];  // 16 KB

  if ((int)blockIdx.x >= gemm_blocks) {  // transpose role (MODE 0 overlap path)
    const int tb = blockIdx.x - gemm_blocks;
    const int e = tb >> 8, rc = tb & 255;
    auto T = reinterpret_cast<unsigned short(*)[72]>(As);
    transpose_tile(T, tsrc + ((size_t)e << 20), tdst + ((size_t)e << 20),
                   (rc >> 4) * 64, (rc & 15) * 64, threadIdx.x);
    return;
  }

  const int e = blockIdx.x & 7;
  const int slot = blockIdx.x >> 3;   // 0..511 per expert
  const int g0 = offsets[e];
  const int m_count = offsets[e + 1] - g0;
  const int m0 = (slot >> 3) * 128;   // 64 m-tiles: covers any routing skew
  if (m0 >= m_count) return;          // uniform early-exit, before any barrier
  const int n0 = (slot & 7) * 128;

  const int tid = threadIdx.x;
  const int wid = tid >> 6, lane = tid & 63;
  const int lrow = lane >> 3;   // 0..7: row within the wave's 8-row stripe
  const int lchunk = lane & 7;  // 16B chunk within the 128B k-row
  const int schunk = lchunk ^ lrow;  // pre-swizzled source chunk (involution)

  const unsigned short* ga[4];
  const unsigned short* gb[4];
  unsigned short* la[4];
  unsigned short* lb[4];
  const unsigned short* WtE = Wt + ((size_t)e << 20);
#pragma unroll
  for (int t = 0; t < 4; t++) {
    const int rbase = t * 32 + wid * 8;  // wave-uniform, multiple of 8
    const int r = rbase + lrow;          // 0..127
    int gr = g0 + m0 + r;
    if (gr > N_TOK - 1) gr = N_TOK - 1;  // clamp partial m-tiles
    const int arow = (MODE == 0) ? perm[gr] : gr;
    ga[t] = Abase + (size_t)arow * 1024 + schunk * 8;
    gb[t] = WtE + (size_t)(n0 + r) * 1024 + schunk * 8;
    la[t] = &As[rbase * 64];  // linear dest, uniform per wave (required)
    lb[t] = &Bs[rbase * 64];
  }

  f32x4 acc[4][4];
  const f32x4 zero4 = {0.f, 0.f, 0.f, 0.f};
#pragma unroll
  for (int i = 0; i < 4; i++)
#pragma unroll
    for (int j = 0; j < 4; j++) acc[i][j] = zero4;

  const int wr = wid >> 1, wc = wid & 1;  // wave tile: 64x64
  const int lr = lane & 15, lk = lane >> 4;

  auto stage = [&]() {
#pragma unroll
    for (int t = 0; t < 4; t++) {
      load_lds16(ga[t], la[t]);
      load_lds16(gb[t], lb[t]);
      ga[t] += 64;
      gb[t] += 64;
    }
  };
  auto compute = [&]() {
#pragma unroll
    for (int kk = 0; kk < 64; kk += 32) {
      bf16x8 af[4], bfr[4];
#pragma unroll
      for (int mf = 0; mf < 4; mf++) {
        const int ra = wr * 64 + mf * 16 + lr;
        const int ca = ((kk >> 3) + lk) ^ (ra & 7);  // swizzled read chunk
        af[mf] = *reinterpret_cast<const bf16x8*>(&As[ra * 64 + ca * 8]);
      }
#pragma unroll
      for (int nf = 0; nf < 4; nf++) {
        const int rb = wc * 64 + nf * 16 + lr;
        const int cb = ((kk >> 3) + lk) ^ (rb & 7);
        bfr[nf] = *reinterpret_cast<const bf16x8*>(&Bs[rb * 64 + cb * 8]);
      }
#pragma unroll
      for (int mf = 0; mf < 4; mf++)
#pragma unroll
        for (int nf = 0; nf < 4; nf++)
          acc[mf][nf] = __builtin_amdgcn_mfma_f32_16x16x32_bf16(
              af[mf], bfr[nf], acc[mf][nf], 0, 0, 0);
    }
  };

  stage();
  __syncthreads();  // vmcnt(0) drain + barrier: tile 0 ready
  for (int kt = 0; kt < 16; kt++) {
    compute();
    if (kt < 15) {
      __syncthreads();  // all waves done reading
      stage();
      __syncthreads();  // next tile ready
    }
  }

  // epilogue: C/D layout col=lane&15, row=(lane>>4)*4+reg [m89]
  const int mlim = m_count - m0;
#pragma unroll
  for (int nf = 0; nf < 4; nf++) {
    const int c = n0 + wc * 64 + nf * 16 + lr;
    const float bval = bias[(e << 10) + c];
#pragma unroll
    for (int mf = 0; mf < 4; mf++) {
#pragma unroll
      for (int j = 0; j < 4; j++) {
        const int lrow2 = wr * 64 + mf * 16 + lk * 4 + j;
        if (lrow2 < mlim) {
          float v = acc[mf][nf][j] + bval;
          if (MODE == 0) {
            v = v > 0.f ? v : 0.f;
            hb[(size_t)(g0 + m0 + lrow2) * 1024 + c] = f32_to_bf16_bits(v);
          } else {
            int token = perm[g0 + m0 + lrow2];
            out[(size_t)token * 1024 + c] = v;
          }
        }
      }
    }
  }
}

// ---------- launch ----------
extern "C" void kernel_launch(void* const* d_in, const int* in_sizes, int n_in,
                              void* d_out, int out_size, void* d_ws, size_t ws_size,
                              hipStream_t stream) {
  const float* x = (const float*)d_in[0];
  const float* Wp = (const float*)d_in[1];
  const float* bp = (const float*)d_in[2];
  const float* W1 = (const float*)d_in[3];
  const float* b1 = (const float*)d_in[4];
  const float* W2 = (const float*)d_in[5];
  const float* b2 = (const float*)d_in[6];

  float* out = (float*)d_out;                      // [8192][1024]
  float* probs = out + (size_t)N_TOK * D_DIM;      // [8192][8]
  float* chosenF = probs + (size_t)N_TOK * E_NUM;  // [8192]

  char* ws = (char*)d_ws;
  int* chosen = (int*)(ws + 0);       // 32 KB
  int* perm = (int*)(ws + 32768);     // 32 KB
  float* WpT = (float*)(ws + 65536);  // 32 KB
  int* offsets = (int*)(ws + 98304);  // 64 B
  const size_t MB16 = 16777216;
  unsigned short* xb = (unsigned short*)(ws + 131072);          // 16 MB
  unsigned short* Wt1 = (unsigned short*)(ws + 131072 + MB16);  // 16 MB
  // overlap path: Wt2 separate (GEMM1 reads Wt1 while W2T is written);
  // sequential fallback: Wt2 aliases Wt1 (written after GEMM1 completes).
  const bool overlap = ws_size >= 131072 + 4 * MB16;
  unsigned short* Wt2 = (unsigned short*)(ws + 131072 + (overlap ? 2 : 1) * MB16);
  unsigned short* hb = (unsigned short*)(ws + 131072 + (overlap ? 3 : 2) * MB16);

  const int GEMM_BLOCKS = E_NUM * 64 * 8;  // 4096: worst-case m coverage x 8 n-tiles

  wpt_kernel<<<32, 256, 0, stream>>>(Wp, WpT);
  routing_w1t_kernel<<<4096, 256, 0, stream>>>(x, WpT, bp, probs, chosenF, chosen,
                                               xb, W1, Wt1);
  scan_scatter_kernel<<<1, 1024, 0, stream>>>(chosen, offsets, perm);
  if (overlap) {
    moe_gemm_kernel<0><<<GEMM_BLOCKS + 2048, 256, 0, stream>>>(
        xb, Wt1, b1, offsets, perm, hb, nullptr, W2, Wt2, GEMM_BLOCKS);
  } else {
    moe_gemm_kernel<0><<<GEMM_BLOCKS, 256, 0, stream>>>(
        xb, Wt1, b1, offsets, perm, hb, nullptr, nullptr, nullptr, GEMM_BLOCKS);
    transpose_cast_kernel<<<dim3(16, 16, 8), 256, 0, stream>>>(W2, Wt2);
  }
  moe_gemm_kernel<1><<<GEMM_BLOCKS, 256, 0, stream>>>(
      hb, Wt2, b2, offsets, perm, nullptr, out, nullptr, nullptr, GEMM_BLOCKS);
}

// Round 6
// 121.425 us; speedup vs baseline: 3.4622x; 1.0648x over previous
//
#include <hip/hip_runtime.h>
#include <stdint.h>

#define N_TOK 8192
#define D_DIM 1024
#define E_NUM 8

typedef float f32x4 __attribute__((ext_vector_type(4)));
typedef __bf16 bf16x8 __attribute__((ext_vector_type(8)));

__device__ __forceinline__ unsigned short f32_to_bf16_bits(float f) {
  union { float f; uint32_t u; } v; v.f = f;
  uint32_t u = v.u;
  uint32_t r = u + 0x7fffu + ((u >> 16) & 1u);  // RNE
  return (unsigned short)(r >> 16);
}

__device__ __forceinline__ void load_lds16(const void* g, void* l) {
  // async global->LDS, 16B/lane, dest = uniform base + lane*16
  __builtin_amdgcn_global_load_lds(
      (const __attribute__((address_space(1))) void*)g,
      (__attribute__((address_space(3))) void*)l, 16, 0, 0);
}

// ---------- shared 64x64 fp32->bf16 transpose tile (LDS-staged) ----------
__device__ __forceinline__ void transpose_tile(unsigned short (*T)[72],
                                               const float* __restrict__ S,
                                               unsigned short* __restrict__ O,
                                               int r0, int c0, int t) {
  const int rr = t >> 4;
  const int cc = (t & 15) * 4;
#pragma unroll
  for (int p = 0; p < 4; p++) {
    int r = p * 16 + rr;
    float4 v = *reinterpret_cast<const float4*>(S + (size_t)(r0 + r) * 1024 + c0 + cc);
    T[cc + 0][r] = f32_to_bf16_bits(v.x);
    T[cc + 1][r] = f32_to_bf16_bits(v.y);
    T[cc + 2][r] = f32_to_bf16_bits(v.z);
    T[cc + 3][r] = f32_to_bf16_bits(v.w);
  }
  __syncthreads();
#pragma unroll
  for (int p = 0; p < 4; p++) {
    int c = p * 16 + rr;
    ushort4 o = *reinterpret_cast<const ushort4*>(&T[c][cc]);
    *reinterpret_cast<ushort4*>(O + (size_t)(c0 + c) * 1024 + r0 + cc) = o;
  }
}

// ---------- Wp [1024][8] -> WpT [8][1024] ----------
__global__ __launch_bounds__(256) void wpt_kernel(const float* __restrict__ Wp,
                                                  float* __restrict__ WpT) {
  int i = blockIdx.x * 256 + threadIdx.x;  // 8192 total
  int e = i >> 10, d = i & 1023;
  WpT[i] = Wp[(size_t)d * E_NUM + e];
}

// ---------- fused: routing (fp64 logits) + x->bf16 + W1 transpose ----------
// bids 0..2047: routing, 4 tokens/block. bids 2048..4095: W1 64x64 transpose tiles.
// fp64 logits so argmax matches the np reference exactly.
// NO global atomics (R3: 8192 same-line atomicAdds serialized ~70us of tail).
__global__ __launch_bounds__(256) void routing_w1t_kernel(
    const float* __restrict__ x, const float* __restrict__ WpT,
    const float* __restrict__ bp, float* __restrict__ probs_out,
    float* __restrict__ chosenF, int* __restrict__ chosen,
    unsigned short* __restrict__ xb,
    const float* __restrict__ W1, unsigned short* __restrict__ W1t) {
  __shared__ __align__(16) unsigned short T[64][72];
  __shared__ __align__(16) float pbuf[4][8];
  if (blockIdx.x >= 2048) {  // transpose role
    const int tb = blockIdx.x - 2048;
    const int e = tb >> 8, rc = tb & 255;
    transpose_tile(T, W1 + ((size_t)e << 20), W1t + ((size_t)e << 20),
                   (rc >> 4) * 64, (rc & 15) * 64, threadIdx.x);
    return;
  }
  const int wave = threadIdx.x >> 6;
  const int lane = threadIdx.x & 63;
  const int token = blockIdx.x * 4 + wave;
  const float* xr = x + (size_t)token * D_DIM;
  unsigned short* xbr = xb + (size_t)token * D_DIM;
  double acc[E_NUM];
#pragma unroll
  for (int e = 0; e < E_NUM; e++) acc[e] = 0.0;
#pragma unroll
  for (int it = 0; it < 4; it++) {
    const int d0 = it * 256 + lane * 4;
    float4 xv = *reinterpret_cast<const float4*>(xr + d0);
    ushort4 o;
    o.x = f32_to_bf16_bits(xv.x);
    o.y = f32_to_bf16_bits(xv.y);
    o.z = f32_to_bf16_bits(xv.z);
    o.w = f32_to_bf16_bits(xv.w);
    *reinterpret_cast<ushort4*>(xbr + d0) = o;
#pragma unroll
    for (int e = 0; e < E_NUM; e++) {
      float4 w = *reinterpret_cast<const float4*>(WpT + (e << 10) + d0);  // coalesced
      acc[e] += (double)xv.x * (double)w.x;
      acc[e] += (double)xv.y * (double)w.y;
      acc[e] += (double)xv.z * (double)w.z;
      acc[e] += (double)xv.w * (double)w.w;
    }
  }
#pragma unroll
  for (int e = 0; e < E_NUM; e++) {
#pragma unroll
    for (int off = 32; off > 0; off >>= 1) acc[e] += __shfl_xor(acc[e], off);
  }
  if (lane == 0) {
    double lg[E_NUM];
#pragma unroll
    for (int e = 0; e < E_NUM; e++) lg[e] = acc[e] + (double)bp[e];
    int best = 0;
    double bv = lg[0];
#pragma unroll
    for (int e = 1; e < E_NUM; e++)
      if (lg[e] > bv) { bv = lg[e]; best = e; }  // strict > == first-max (jnp.argmax)
    double s = 0.0, ex[E_NUM];
#pragma unroll
    for (int e = 0; e < E_NUM; e++) { ex[e] = exp(lg[e] - bv); s += ex[e]; }
    double inv = 1.0 / s;
#pragma unroll
    for (int e = 0; e < E_NUM; e++) pbuf[wave][e] = (float)(ex[e] * inv);
    chosenF[token] = (float)best;
    chosen[token] = best;
  }
  __syncthreads();
  if (threadIdx.x < 8) {  // coalesced 128B probs store per block
    float4 v = *reinterpret_cast<const float4*>(
        &pbuf[threadIdx.x >> 1][(threadIdx.x & 1) * 4]);
    reinterpret_cast<float4*>(probs_out + (size_t)blockIdx.x * 32)[threadIdx.x] = v;
  }
}

// ---------- histogram + scan + scatter, one block, LDS atomics only ----------
__global__ __launch_bounds__(1024) void scan_scatter_kernel(
    const int* __restrict__ chosen, int* __restrict__ offsets,
    int* __restrict__ perm) {
  __shared__ int hist[E_NUM];
  __shared__ int curs[E_NUM];
  const int t = threadIdx.x;
  if (t < E_NUM) hist[t] = 0;
  __syncthreads();
  for (int n = t; n < N_TOK; n += 1024) atomicAdd(&hist[chosen[n]], 1);
  __syncthreads();
  if (t == 0) {
    int off = 0;
    for (int e = 0; e < E_NUM; e++) { offsets[e] = off; curs[e] = off; off += hist[e]; }
    offsets[E_NUM] = off;
  }
  __syncthreads();
  for (int n = t; n < N_TOK; n += 1024) {
    int e = chosen[n];
    int p = atomicAdd(&curs[e], 1);  // in-group order irrelevant
    perm[p] = n;
  }
}

// ---------- standalone per-expert transpose (sequential fallback path) ----------
__global__ __launch_bounds__(256) void transpose_cast_kernel(
    const float* __restrict__ src, unsigned short* __restrict__ dst) {
  __shared__ __align__(16) unsigned short T[64][72];
  const int e = blockIdx.z;
  transpose_tile(T, src + ((size_t)e << 20), dst + ((size_t)e << 20),
                 blockIdx.y * 64, blockIdx.x * 64, threadIdx.x);
}

// ---------- grouped GEMM: 128x64 tile, BK=64, 4 waves ----------
// R6: issue-early double-buffered staging (catalog min-2-phase, T3-lite):
//   stage(next buf) BEFORE compute(cur); ONE __syncthreads per K-step.
//   The vmcnt(0) drain at the barrier now waits only for loads that already
//   had the whole compute phase in flight -> global latency hidden.
//   (R5 lesson = m230/m233 regime gate: naive {compute;bar;stage;bar} is
//   stage-latency-bound, so the T2 swizzle was null. With stage amortized,
//   ds_read is on the critical path -> swizzle now pays. Keep it.)
// BN=64 -> 1024 active blocks (4/CU grid-wise; LDS 48KB caps 3/CU).
// T2 swizzle, rule #21 both-sides: linear LDS dest, source chunk ^= lrow,
// read chunk ^= (row&7).
// MODE 0: h = relu(x[perm] @ W1t^T + b1) -> hb   MODE 1: out[perm] = hb @ W2t^T + b2
template <int MODE>
__global__ __launch_bounds__(256) void moe_gemm_kernel(
    const unsigned short* __restrict__ Abase,  // xb (MODE0) / hb (MODE1)
    const unsigned short* __restrict__ Wt,     // bf16 [E][1024(n)][1024(k)]
    const float* __restrict__ bias,            // [E][1024]
    const int* __restrict__ offsets, const int* __restrict__ perm,
    unsigned short* __restrict__ hb, float* __restrict__ out,
    const float* __restrict__ tsrc, unsigned short* __restrict__ tdst,
    int gemm_blocks) {
  __shared__ __align__(16) unsigned short As[2][128 * 64];  // 32 KB
  __shared__ __align__(16) unsigned short Bs[2][64 * 64];   // 16 KB

  if ((int)blockIdx.x >= gemm_blocks) {  // transpose role (MODE 0 overlap path)
    const int tb = blockIdx.x - gemm_blocks;
    const int e = tb >> 8, rc = tb & 255;
    auto T = reinterpret_cast<unsigned short(*)[72]>(&As[0][0]);
    transpose_tile(T, tsrc + ((size_t)e << 20), tdst + ((size_t)e << 20),
                   (rc >> 4) * 64, (rc & 15) * 64, threadIdx.x);
    return;
  }

  const int e = blockIdx.x & 7;
  const int slot = blockIdx.x >> 3;   // 0..1023 per expert
  const int g0 = offsets[e];
  const int m_count = offsets[e + 1] - g0;
  const int m0 = (slot >> 4) * 128;   // 64 m-tiles: covers any routing skew
  if (m0 >= m_count) return;          // uniform early-exit, before any barrier
  const int n0 = (slot & 15) * 64;

  const int tid = threadIdx.x;
  const int wid = tid >> 6, lane = tid & 63;
  const int lrow = lane >> 3;        // 0..7: row within the wave's 8-row stripe
  const int lchunk = lane & 7;       // 16B chunk within the 128B k-row
  const int schunk = lchunk ^ lrow;  // pre-swizzled source chunk (involution)

  const unsigned short* ga[4];
  const unsigned short* gb[2];
  int abase[4], bbase[2];
  const unsigned short* WtE = Wt + ((size_t)e << 20);
#pragma unroll
  for (int t = 0; t < 4; t++) {
    const int rbase = t * 32 + wid * 8;  // wave-uniform, multiple of 8
    const int r = rbase + lrow;          // 0..127
    int gr = g0 + m0 + r;
    if (gr > N_TOK - 1) gr = N_TOK - 1;  // clamp partial m-tiles
    const int arow = (MODE == 0) ? perm[gr] : gr;
    ga[t] = Abase + (size_t)arow * 1024 + schunk * 8;
    abase[t] = rbase * 64;  // linear LDS dest, wave-uniform (required)
  }
#pragma unroll
  for (int t = 0; t < 2; t++) {
    const int rbase = t * 32 + wid * 8;
    const int r = rbase + lrow;  // 0..63
    gb[t] = WtE + (size_t)(n0 + r) * 1024 + schunk * 8;
    bbase[t] = rbase * 64;
  }

  f32x4 acc[4][2];
  const f32x4 zero4 = {0.f, 0.f, 0.f, 0.f};
#pragma unroll
  for (int i = 0; i < 4; i++)
#pragma unroll
    for (int j = 0; j < 2; j++) acc[i][j] = zero4;

  const int wr = wid >> 1, wc = wid & 1;  // wave tile: 64 rows x 32 cols
  const int lr = lane & 15, lk = lane >> 4;

  auto stage = [&](int buf) {
#pragma unroll
    for (int t = 0; t < 4; t++) {
      load_lds16(ga[t], &As[buf][abase[t]]);
      ga[t] += 64;
    }
#pragma unroll
    for (int t = 0; t < 2; t++) {
      load_lds16(gb[t], &Bs[buf][bbase[t]]);
      gb[t] += 64;
    }
  };
  auto compute = [&](int buf) {
#pragma unroll
    for (int kk = 0; kk < 64; kk += 32) {
      bf16x8 af[4], bfr[2];
#pragma unroll
      for (int mf = 0; mf < 4; mf++) {
        const int ra = wr * 64 + mf * 16 + lr;
        const int ca = ((kk >> 3) + lk) ^ (ra & 7);  // swizzled read chunk
        af[mf] = *reinterpret_cast<const bf16x8*>(&As[buf][ra * 64 + ca * 8]);
      }
#pragma unroll
      for (int nf = 0; nf < 2; nf++) {
        const int rb = wc * 32 + nf * 16 + lr;
        const int cb = ((kk >> 3) + lk) ^ (rb & 7);
        bfr[nf] = *reinterpret_cast<const bf16x8*>(&Bs[buf][rb * 64 + cb * 8]);
      }
#pragma unroll
      for (int mf = 0; mf < 4; mf++)
#pragma unroll
        for (int nf = 0; nf < 2; nf++)
          acc[mf][nf] = __builtin_amdgcn_mfma_f32_16x16x32_bf16(
              af[mf], bfr[nf], acc[mf][nf], 0, 0, 0);
    }
  };

  // prologue: stage K-tile 0 into buf 0; drain; then issue-early loop
  stage(0);
  __syncthreads();
  int cur = 0;
  for (int kt = 0; kt < 16; kt++) {
    if (kt < 15) stage(cur ^ 1);  // next tile's loads fly during compute
    compute(cur);
    if (kt < 15) __syncthreads();  // vmcnt(0)+barrier: next tile ready
    cur ^= 1;
  }

  // epilogue: C/D layout col=lane&15, row=(lane>>4)*4+reg [m89]
  const int mlim = m_count - m0;
#pragma unroll
  for (int nf = 0; nf < 2; nf++) {
    const int c = n0 + wc * 32 + nf * 16 + lr;
    const float bval = bias[(e << 10) + c];
#pragma unroll
    for (int mf = 0; mf < 4; mf++) {
#pragma unroll
      for (int j = 0; j < 4; j++) {
        const int lrow2 = wr * 64 + mf * 16 + lk * 4 + j;
        if (lrow2 < mlim) {
          float v = acc[mf][nf][j] + bval;
          if (MODE == 0) {
            v = v > 0.f ? v : 0.f;
            hb[(size_t)(g0 + m0 + lrow2) * 1024 + c] = f32_to_bf16_bits(v);
          } else {
            int token = perm[g0 + m0 + lrow2];
            out[(size_t)token * 1024 + c] = v;
          }
        }
      }
    }
  }
}

// ---------- launch ----------
extern "C" void kernel_launch(void* const* d_in, const int* in_sizes, int n_in,
                              void* d_out, int out_size, void* d_ws, size_t ws_size,
                              hipStream_t stream) {
  const float* x = (const float*)d_in[0];
  const float* Wp = (const float*)d_in[1];
  const float* bp = (const float*)d_in[2];
  const float* W1 = (const float*)d_in[3];
  const float* b1 = (const float*)d_in[4];
  const float* W2 = (const float*)d_in[5];
  const float* b2 = (const float*)d_in[6];

  float* out = (float*)d_out;                      // [8192][1024]
  float* probs = out + (size_t)N_TOK * D_DIM;      // [8192][8]
  float* chosenF = probs + (size_t)N_TOK * E_NUM;  // [8192]

  char* ws = (char*)d_ws;
  int* chosen = (int*)(ws + 0);       // 32 KB
  int* perm = (int*)(ws + 32768);     // 32 KB
  float* WpT = (float*)(ws + 65536);  // 32 KB
  int* offsets = (int*)(ws + 98304);  // 64 B
  const size_t MB16 = 16777216;
  unsigned short* xb = (unsigned short*)(ws + 131072);          // 16 MB
  unsigned short* Wt1 = (unsigned short*)(ws + 131072 + MB16);  // 16 MB
  // overlap path: Wt2 separate (GEMM1 reads Wt1 while W2T is written);
  // sequential fallback: Wt2 aliases Wt1 (written after GEMM1 completes).
  const bool overlap = ws_size >= 131072 + 4 * MB16;
  unsigned short* Wt2 = (unsigned short*)(ws + 131072 + (overlap ? 2 : 1) * MB16);
  unsigned short* hb = (unsigned short*)(ws + 131072 + (overlap ? 3 : 2) * MB16);

  const int GEMM_BLOCKS = E_NUM * 64 * 16;  // 8192: worst-case m coverage x 16 n-tiles

  wpt_kernel<<<32, 256, 0, stream>>>(Wp, WpT);
  routing_w1t_kernel<<<4096, 256, 0, stream>>>(x, WpT, bp, probs, chosenF, chosen,
                                               xb, W1, Wt1);
  scan_scatter_kernel<<<1, 1024, 0, stream>>>(chosen, offsets, perm);
  if (overlap) {
    moe_gemm_kernel<0><<<GEMM_BLOCKS + 2048, 256, 0, stream>>>(
        xb, Wt1, b1, offsets, perm, hb, nullptr, W2, Wt2, GEMM_BLOCKS);
  } else {
    moe_gemm_kernel<0><<<GEMM_BLOCKS, 256, 0, stream>>>(
        xb, Wt1, b1, offsets, perm, hb, nullptr, nullptr, nullptr, GEMM_BLOCKS);
    transpose_cast_kernel<<<dim3(16, 16, 8), 256, 0, stream>>>(W2, Wt2);
  }
  moe_gemm_kernel<1><<<GEMM_BLOCKS, 256, 0, stream>>>(
      hb, Wt2, b2, offsets, perm, nullptr, out, nullptr, nullptr, GEMM_BLOCKS);
}

// Round 7
// 117.680 us; speedup vs baseline: 3.5724x; 1.0318x over previous
//
#include <hip/hip_runtime.h>
#include <stdint.h>

#define N_TOK 8192
#define D_DIM 1024
#define E_NUM 8

typedef float f32x4 __attribute__((ext_vector_type(4)));
typedef __bf16 bf16x8 __attribute__((ext_vector_type(8)));

__device__ __forceinline__ unsigned short f32_to_bf16_bits(float f) {
  union { float f; uint32_t u; } v; v.f = f;
  uint32_t u = v.u;
  uint32_t r = u + 0x7fffu + ((u >> 16) & 1u);  // RNE
  return (unsigned short)(r >> 16);
}

__device__ __forceinline__ void load_lds16(const void* g, void* l) {
  // async global->LDS, 16B/lane, dest = uniform base + lane*16
  __builtin_amdgcn_global_load_lds(
      (const __attribute__((address_space(1))) void*)g,
      (__attribute__((address_space(3))) void*)l, 16, 0, 0);
}

// ---------- shared 64x64 fp32->bf16 transpose tile (LDS-staged) ----------
__device__ __forceinline__ void transpose_tile(unsigned short (*T)[72],
                                               const float* __restrict__ S,
                                               unsigned short* __restrict__ O,
                                               int r0, int c0, int t) {
  const int rr = t >> 4;
  const int cc = (t & 15) * 4;
#pragma unroll
  for (int p = 0; p < 4; p++) {
    int r = p * 16 + rr;
    float4 v = *reinterpret_cast<const float4*>(S + (size_t)(r0 + r) * 1024 + c0 + cc);
    T[cc + 0][r] = f32_to_bf16_bits(v.x);
    T[cc + 1][r] = f32_to_bf16_bits(v.y);
    T[cc + 2][r] = f32_to_bf16_bits(v.z);
    T[cc + 3][r] = f32_to_bf16_bits(v.w);
  }
  __syncthreads();
#pragma unroll
  for (int p = 0; p < 4; p++) {
    int c = p * 16 + rr;
    ushort4 o = *reinterpret_cast<const ushort4*>(&T[c][cc]);
    *reinterpret_cast<ushort4*>(O + (size_t)(c0 + c) * 1024 + r0 + cc) = o;
  }
}

// ---------- Wp [1024][8] -> WpT [8][1024] ----------
__global__ __launch_bounds__(256) void wpt_kernel(const float* __restrict__ Wp,
                                                  float* __restrict__ WpT) {
  int i = blockIdx.x * 256 + threadIdx.x;  // 8192 total
  int e = i >> 10, d = i & 1023;
  WpT[i] = Wp[(size_t)d * E_NUM + e];
}

// ---------- fused: routing (fp64 logits) + x->bf16 + W1 transpose ----------
// bids 0..2047: routing, 4 tokens/block. bids 2048..4095: W1 64x64 transpose tiles.
// fp64 logits so argmax matches the np reference exactly.
// NO global atomics (R3: 8192 same-line atomicAdds serialized ~70us of tail).
__global__ __launch_bounds__(256) void routing_w1t_kernel(
    const float* __restrict__ x, const float* __restrict__ WpT,
    const float* __restrict__ bp, float* __restrict__ probs_out,
    float* __restrict__ chosenF, int* __restrict__ chosen,
    unsigned short* __restrict__ xb,
    const float* __restrict__ W1, unsigned short* __restrict__ W1t) {
  __shared__ __align__(16) unsigned short T[64][72];
  __shared__ __align__(16) float pbuf[4][8];
  if (blockIdx.x >= 2048) {  // transpose role
    const int tb = blockIdx.x - 2048;
    const int e = tb >> 8, rc = tb & 255;
    transpose_tile(T, W1 + ((size_t)e << 20), W1t + ((size_t)e << 20),
                   (rc >> 4) * 64, (rc & 15) * 64, threadIdx.x);
    return;
  }
  const int wave = threadIdx.x >> 6;
  const int lane = threadIdx.x & 63;
  const int token = blockIdx.x * 4 + wave;
  const float* xr = x + (size_t)token * D_DIM;
  unsigned short* xbr = xb + (size_t)token * D_DIM;
  double acc[E_NUM];
#pragma unroll
  for (int e = 0; e < E_NUM; e++) acc[e] = 0.0;
#pragma unroll
  for (int it = 0; it < 4; it++) {
    const int d0 = it * 256 + lane * 4;
    float4 xv = *reinterpret_cast<const float4*>(xr + d0);
    ushort4 o;
    o.x = f32_to_bf16_bits(xv.x);
    o.y = f32_to_bf16_bits(xv.y);
    o.z = f32_to_bf16_bits(xv.z);
    o.w = f32_to_bf16_bits(xv.w);
    *reinterpret_cast<ushort4*>(xbr + d0) = o;
#pragma unroll
    for (int e = 0; e < E_NUM; e++) {
      float4 w = *reinterpret_cast<const float4*>(WpT + (e << 10) + d0);  // coalesced
      acc[e] += (double)xv.x * (double)w.x;
      acc[e] += (double)xv.y * (double)w.y;
      acc[e] += (double)xv.z * (double)w.z;
      acc[e] += (double)xv.w * (double)w.w;
    }
  }
#pragma unroll
  for (int e = 0; e < E_NUM; e++) {
#pragma unroll
    for (int off = 32; off > 0; off >>= 1) acc[e] += __shfl_xor(acc[e], off);
  }
  if (lane == 0) {
    double lg[E_NUM];
#pragma unroll
    for (int e = 0; e < E_NUM; e++) lg[e] = acc[e] + (double)bp[e];
    int best = 0;
    double bv = lg[0];
#pragma unroll
    for (int e = 1; e < E_NUM; e++)
      if (lg[e] > bv) { bv = lg[e]; best = e; }  // strict > == first-max (jnp.argmax)
    double s = 0.0, ex[E_NUM];
#pragma unroll
    for (int e = 0; e < E_NUM; e++) { ex[e] = exp(lg[e] - bv); s += ex[e]; }
    double inv = 1.0 / s;
#pragma unroll
    for (int e = 0; e < E_NUM; e++) pbuf[wave][e] = (float)(ex[e] * inv);
    chosenF[token] = (float)best;
    chosen[token] = best;
  }
  __syncthreads();
  if (threadIdx.x < 8) {  // coalesced 128B probs store per block
    float4 v = *reinterpret_cast<const float4*>(
        &pbuf[threadIdx.x >> 1][(threadIdx.x & 1) * 4]);
    reinterpret_cast<float4*>(probs_out + (size_t)blockIdx.x * 32)[threadIdx.x] = v;
  }
}

// ---------- histogram + scan + scatter, one block, LDS atomics only ----------
__global__ __launch_bounds__(1024) void scan_scatter_kernel(
    const int* __restrict__ chosen, int* __restrict__ offsets,
    int* __restrict__ perm) {
  __shared__ int hist[E_NUM];
  __shared__ int curs[E_NUM];
  const int t = threadIdx.x;
  if (t < E_NUM) hist[t] = 0;
  __syncthreads();
  for (int n = t; n < N_TOK; n += 1024) atomicAdd(&hist[chosen[n]], 1);
  __syncthreads();
  if (t == 0) {
    int off = 0;
    for (int e = 0; e < E_NUM; e++) { offsets[e] = off; curs[e] = off; off += hist[e]; }
    offsets[E_NUM] = off;
  }
  __syncthreads();
  for (int n = t; n < N_TOK; n += 1024) {
    int e = chosen[n];
    int p = atomicAdd(&curs[e], 1);  // in-group order irrelevant
    perm[p] = n;
  }
}

// ---------- standalone per-expert transpose (sequential fallback path) ----------
__global__ __launch_bounds__(256) void transpose_cast_kernel(
    const float* __restrict__ src, unsigned short* __restrict__ dst) {
  __shared__ __align__(16) unsigned short T[64][72];
  const int e = blockIdx.z;
  transpose_tile(T, src + ((size_t)e << 20), dst + ((size_t)e << 20),
                 blockIdx.y * 64, blockIdx.x * 64, threadIdx.x);
}

// ---------- grouped GEMM: 128x64 tile, BK=64, 4 waves ----------
// R7: T4 counted-vmcnt pipeline (AITER 2-barrier K-loop form) — never drain
// vmcnt to 0 in the main loop:
//   prologue: stage(tile0), stage(tile1)
//   steady:   s_waitcnt vmcnt(6)   <- tile t's 6 loads done, t+1's 6 in flight
//             s_barrier; MFMA(tile t) [setprio 1]; s_barrier
//             stage(tile t+2)      <- has TWO compute phases to land
// "memory" clobber on the waitcnt asm orders the following ds_reads (memory
// ops — rule #18's hazard is register-only MFMA, not loads); sched_barrier(0)
// added after each waitcnt as extra fence. Early-exit is block-uniform, so
// raw-barrier wave counts are consistent.
// Keeps: T2 swizzle (src chunk ^= lrow, read chunk ^= row&7, linear LDS dest),
// BN=64/1024 active blocks, expert-per-XCD bid mapping, worst-case skew grid.
// MODE 0: h = relu(x[perm] @ W1t^T + b1) -> hb   MODE 1: out[perm] = hb @ W2t^T + b2
template <int MODE>
__global__ __launch_bounds__(256) void moe_gemm_kernel(
    const unsigned short* __restrict__ Abase,  // xb (MODE0) / hb (MODE1)
    const unsigned short* __restrict__ Wt,     // bf16 [E][1024(n)][1024(k)]
    const float* __restrict__ bias,            // [E][1024]
    const int* __restrict__ offsets, const int* __restrict__ perm,
    unsigned short* __restrict__ hb, float* __restrict__ out,
    const float* __restrict__ tsrc, unsigned short* __restrict__ tdst,
    int gemm_blocks) {
  __shared__ __align__(16) unsigned short As[2][128 * 64];  // 32 KB
  __shared__ __align__(16) unsigned short Bs[2][64 * 64];   // 16 KB

  if ((int)blockIdx.x >= gemm_blocks) {  // transpose role (MODE 0 overlap path)
    const int tb = blockIdx.x - gemm_blocks;
    const int e = tb >> 8, rc = tb & 255;
    auto T = reinterpret_cast<unsigned short(*)[72]>(&As[0][0]);
    transpose_tile(T, tsrc + ((size_t)e << 20), tdst + ((size_t)e << 20),
                   (rc >> 4) * 64, (rc & 15) * 64, threadIdx.x);
    return;
  }

  const int e = blockIdx.x & 7;
  const int slot = blockIdx.x >> 3;   // 0..1023 per expert
  const int g0 = offsets[e];
  const int m_count = offsets[e + 1] - g0;
  const int m0 = (slot >> 4) * 128;   // 64 m-tiles: covers any routing skew
  if (m0 >= m_count) return;          // uniform early-exit, before any barrier
  const int n0 = (slot & 15) * 64;

  const int tid = threadIdx.x;
  const int wid = tid >> 6, lane = tid & 63;
  const int lrow = lane >> 3;        // 0..7: row within the wave's 8-row stripe
  const int lchunk = lane & 7;       // 16B chunk within the 128B k-row
  const int schunk = lchunk ^ lrow;  // pre-swizzled source chunk (involution)

  const unsigned short* ga[4];
  const unsigned short* gb[2];
  int abase[4], bbase[2];
  const unsigned short* WtE = Wt + ((size_t)e << 20);
#pragma unroll
  for (int t = 0; t < 4; t++) {
    const int rbase = t * 32 + wid * 8;  // wave-uniform, multiple of 8
    const int r = rbase + lrow;          // 0..127
    int gr = g0 + m0 + r;
    if (gr > N_TOK - 1) gr = N_TOK - 1;  // clamp partial m-tiles
    const int arow = (MODE == 0) ? perm[gr] : gr;
    ga[t] = Abase + (size_t)arow * 1024 + schunk * 8;
    abase[t] = rbase * 64;  // linear LDS dest, wave-uniform (required)
  }
#pragma unroll
  for (int t = 0; t < 2; t++) {
    const int rbase = t * 32 + wid * 8;
    const int r = rbase + lrow;  // 0..63
    gb[t] = WtE + (size_t)(n0 + r) * 1024 + schunk * 8;
    bbase[t] = rbase * 64;
  }

  f32x4 acc[4][2];
  const f32x4 zero4 = {0.f, 0.f, 0.f, 0.f};
#pragma unroll
  for (int i = 0; i < 4; i++)
#pragma unroll
    for (int j = 0; j < 2; j++) acc[i][j] = zero4;

  const int wr = wid >> 1, wc = wid & 1;  // wave tile: 64 rows x 32 cols
  const int lr = lane & 15, lk = lane >> 4;

  auto stage = [&](int buf) {
#pragma unroll
    for (int t = 0; t < 4; t++) {
      load_lds16(ga[t], &As[buf][abase[t]]);
      ga[t] += 64;
    }
#pragma unroll
    for (int t = 0; t < 2; t++) {
      load_lds16(gb[t], &Bs[buf][bbase[t]]);
      gb[t] += 64;
    }
  };
  auto compute = [&](int buf) {
#pragma unroll
    for (int kk = 0; kk < 64; kk += 32) {
      bf16x8 af[4], bfr[2];
#pragma unroll
      for (int mf = 0; mf < 4; mf++) {
        const int ra = wr * 64 + mf * 16 + lr;
        const int ca = ((kk >> 3) + lk) ^ (ra & 7);  // swizzled read chunk
        af[mf] = *reinterpret_cast<const bf16x8*>(&As[buf][ra * 64 + ca * 8]);
      }
#pragma unroll
      for (int nf = 0; nf < 2; nf++) {
        const int rb = wc * 32 + nf * 16 + lr;
        const int cb = ((kk >> 3) + lk) ^ (rb & 7);
        bfr[nf] = *reinterpret_cast<const bf16x8*>(&Bs[buf][rb * 64 + cb * 8]);
      }
#pragma unroll
      for (int mf = 0; mf < 4; mf++)
#pragma unroll
        for (int nf = 0; nf < 2; nf++)
          acc[mf][nf] = __builtin_amdgcn_mfma_f32_16x16x32_bf16(
              af[mf], bfr[nf], acc[mf][nf], 0, 0, 0);
    }
  };

  // T4 counted-vmcnt pipeline: 2 tiles staged ahead, never vmcnt(0) mid-loop
  stage(0);
  stage(1);
#pragma unroll
  for (int kt = 0; kt < 16; kt++) {
    if (kt < 15) {
      asm volatile("s_waitcnt vmcnt(6)" ::: "memory");
    } else {
      asm volatile("s_waitcnt vmcnt(0)" ::: "memory");
    }
    __builtin_amdgcn_sched_barrier(0);
    __builtin_amdgcn_s_barrier();  // tile kt ready for all waves
    __builtin_amdgcn_s_setprio(1);
    compute(kt & 1);
    __builtin_amdgcn_s_setprio(0);
    __builtin_amdgcn_s_barrier();  // all waves done reading buf[kt&1]
    if (kt < 14) stage(kt & 1);    // tile kt+2 overwrites buf[kt&1]
  }

  // epilogue: C/D layout col=lane&15, row=(lane>>4)*4+reg [m89]
  const int mlim = m_count - m0;
#pragma unroll
  for (int nf = 0; nf < 2; nf++) {
    const int c = n0 + wc * 32 + nf * 16 + lr;
    const float bval = bias[(e << 10) + c];
#pragma unroll
    for (int mf = 0; mf < 4; mf++) {
#pragma unroll
      for (int j = 0; j < 4; j++) {
        const int lrow2 = wr * 64 + mf * 16 + lk * 4 + j;
        if (lrow2 < mlim) {
          float v = acc[mf][nf][j] + bval;
          if (MODE == 0) {
            v = v > 0.f ? v : 0.f;
            hb[(size_t)(g0 + m0 + lrow2) * 1024 + c] = f32_to_bf16_bits(v);
          } else {
            int token = perm[g0 + m0 + lrow2];
            out[(size_t)token * 1024 + c] = v;
          }
        }
      }
    }
  }
}

// ---------- launch ----------
extern "C" void kernel_launch(void* const* d_in, const int* in_sizes, int n_in,
                              void* d_out, int out_size, void* d_ws, size_t ws_size,
                              hipStream_t stream) {
  const float* x = (const float*)d_in[0];
  const float* Wp = (const float*)d_in[1];
  const float* bp = (const float*)d_in[2];
  const float* W1 = (const float*)d_in[3];
  const float* b1 = (const float*)d_in[4];
  const float* W2 = (const float*)d_in[5];
  const float* b2 = (const float*)d_in[6];

  float* out = (float*)d_out;                      // [8192][1024]
  float* probs = out + (size_t)N_TOK * D_DIM;      // [8192][8]
  float* chosenF = probs + (size_t)N_TOK * E_NUM;  // [8192]

  char* ws = (char*)d_ws;
  int* chosen = (int*)(ws + 0);       // 32 KB
  int* perm = (int*)(ws + 32768);     // 32 KB
  float* WpT = (float*)(ws + 65536);  // 32 KB
  int* offsets = (int*)(ws + 98304);  // 64 B
  const size_t MB16 = 16777216;
  unsigned short* xb = (unsigned short*)(ws + 131072);          // 16 MB
  unsigned short* Wt1 = (unsigned short*)(ws + 131072 + MB16);  // 16 MB
  // overlap path: Wt2 separate (GEMM1 reads Wt1 while W2T is written);
  // sequential fallback: Wt2 aliases Wt1 (written after GEMM1 completes).
  const bool overlap = ws_size >= 131072 + 4 * MB16;
  unsigned short* Wt2 = (unsigned short*)(ws + 131072 + (overlap ? 2 : 1) * MB16);
  unsigned short* hb = (unsigned short*)(ws + 131072 + (overlap ? 3 : 2) * MB16);

  const int GEMM_BLOCKS = E_NUM * 64 * 16;  // 8192: worst-case m coverage x 16 n-tiles

  wpt_kernel<<<32, 256, 0, stream>>>(Wp, WpT);
  routing_w1t_kernel<<<4096, 256, 0, stream>>>(x, WpT, bp, probs, chosenF, chosen,
                                               xb, W1, Wt1);
  scan_scatter_kernel<<<1, 1024, 0, stream>>>(chosen, offsets, perm);
  if (overlap) {
    moe_gemm_kernel<0><<<GEMM_BLOCKS + 2048, 256, 0, stream>>>(
        xb, Wt1, b1, offsets, perm, hb, nullptr, W2, Wt2, GEMM_BLOCKS);
  } else {
    moe_gemm_kernel<0><<<GEMM_BLOCKS, 256, 0, stream>>>(
        xb, Wt1, b1, offsets, perm, hb, nullptr, nullptr, nullptr, GEMM_BLOCKS);
    transpose_cast_kernel<<<dim3(16, 16, 8), 256, 0, stream>>>(W2, Wt2);
  }
  moe_gemm_kernel<1><<<GEMM_BLOCKS, 256, 0, stream>>>(
      hb, Wt2, b2, offsets, perm, nullptr, out, nullptr, nullptr, GEMM_BLOCKS);
}